// Round 1
// baseline (669.635 us; speedup 1.0000x reference)
//
#include <hip/hip_runtime.h>
#include <cstdint>
#include <cstddef>

#define S_LEN 2048
#define SCALE_F 0.07216878364870323f  // 1/sqrt(192)

typedef __attribute__((ext_vector_type(8))) short short8;
typedef __attribute__((ext_vector_type(4))) float f32x4;
typedef __attribute__((ext_vector_type(4))) unsigned short ushort4v;

__device__ __forceinline__ unsigned short f2bf(float f) {
  unsigned int u = __builtin_bit_cast(unsigned int, f);
  u += 0x7FFFu + ((u >> 16) & 1u);
  return (unsigned short)(u >> 16);
}
__device__ __forceinline__ float bf2f(unsigned short h) {
  unsigned int u = ((unsigned int)h) << 16;
  return __builtin_bit_cast(float, u);
}

// ---------------- elementwise kernels ----------------

__global__ void k_cast_bf16(const float* __restrict__ src, unsigned short* __restrict__ dst, int n4) {
  int i = blockIdx.x * 256 + threadIdx.x;
  if (i >= n4) return;
  const float4 v = reinterpret_cast<const float4*>(src)[i];
  ushort4v o = { f2bf(v.x), f2bf(v.y), f2bf(v.z), f2bf(v.w) };
  reinterpret_cast<ushort4v*>(dst)[i] = o;
}

__global__ void k_rope_table(const float* __restrict__ freq, float* __restrict__ tab, int n) {
  int i = blockIdx.x * 256 + threadIdx.x;
  if (i >= n) return;
  float f = freq[i];
  tab[2 * i] = cosf(f);
  tab[2 * i + 1] = sinf(f);
}

// src: K x N f32  ->  dst: N x K bf16   (K, N multiples of 64)
__global__ __launch_bounds__(256) void k_transpose_cast(
    const float* __restrict__ src, unsigned short* __restrict__ dst, int K, int N) {
  __shared__ __align__(16) unsigned short tile[64][72];
  const int tid = threadIdx.x;
  const int kb = blockIdx.y * 64, nb = blockIdx.x * 64;
  #pragma unroll
  for (int i = 0; i < 4; ++i) {
    int idx = i * 256 + tid;
    int row = idx >> 4, c4 = (idx & 15) << 2;
    const float4 v = *reinterpret_cast<const float4*>(&src[(size_t)(kb + row) * N + nb + c4]);
    tile[row][c4 + 0] = f2bf(v.x);
    tile[row][c4 + 1] = f2bf(v.y);
    tile[row][c4 + 2] = f2bf(v.z);
    tile[row][c4 + 3] = f2bf(v.w);
  }
  __syncthreads();
  #pragma unroll
  for (int i = 0; i < 4; ++i) {
    int idx = i * 256 + tid;
    int n = idx >> 4, kc = (idx & 15) << 2;
    ushort4v o = { tile[kc + 0][n], tile[kc + 1][n], tile[kc + 2][n], tile[kc + 3][n] };
    *reinterpret_cast<ushort4v*>(&dst[(size_t)(nb + n) * K + kb + kc]) = o;
  }
}

__global__ void k_rope_kr(const unsigned short* __restrict__ raw, const float* __restrict__ tab,
                          unsigned short* __restrict__ out, int npairs) {
  int idx = blockIdx.x * 256 + threadIdx.x;
  if (idx >= npairs) return;
  int bs = idx >> 5, p = idx & 31;
  int s = bs & (S_LEN - 1);
  float c = tab[(s * 32 + p) * 2], sn = tab[(s * 32 + p) * 2 + 1];
  float x1 = bf2f(raw[bs * 64 + 2 * p]), x2 = bf2f(raw[bs * 64 + 2 * p + 1]);
  out[bs * 64 + 2 * p] = f2bf(x1 * c - x2 * sn);
  out[bs * 64 + 2 * p + 1] = f2bf(x1 * sn + x2 * c);
}

// ---------------- GEMM: C[M,N] = A[M,K](bf16) * Bt[N,K]^T(bf16) + bias ----------------
// 128x128 tile, BK=32, 4 waves each 64x64 via 4x4 16x16x32 MFMA fragments.
template <int OUT_BF16>
__global__ __launch_bounds__(256) void k_gemm_bt(
    const unsigned short* __restrict__ A, const unsigned short* __restrict__ Bt,
    const float* __restrict__ bias, void* __restrict__ Cout, int M, int N, int K) {
  __shared__ __align__(16) unsigned short As[128][40];
  __shared__ __align__(16) unsigned short Bs[128][40];
  const int tid = threadIdx.x;
  const int lane = tid & 63, wid = tid >> 6;
  const int wr = wid >> 1, wc = wid & 1;
  const int m0 = blockIdx.y << 7, n0 = blockIdx.x << 7;
  const int l15 = lane & 15, g = lane >> 4;
  f32x4 acc[4][4];
  #pragma unroll
  for (int m = 0; m < 4; ++m)
    #pragma unroll
    for (int n = 0; n < 4; ++n) acc[m][n] = f32x4{0.f, 0.f, 0.f, 0.f};
  for (int k0 = 0; k0 < K; k0 += 32) {
    #pragma unroll
    for (int i = 0; i < 2; ++i) {
      int c = tid + (i << 8);
      int row = c >> 2, cc = (c & 3) << 3;
      int4 av = *reinterpret_cast<const int4*>(&A[(size_t)(m0 + row) * K + k0 + cc]);
      *reinterpret_cast<int4*>(&As[row][cc]) = av;
      int4 bv = make_int4(0, 0, 0, 0);
      if (n0 + row < N)
        bv = *reinterpret_cast<const int4*>(&Bt[(size_t)(n0 + row) * K + k0 + cc]);
      *reinterpret_cast<int4*>(&Bs[row][cc]) = bv;
    }
    __syncthreads();
    short8 af[4], bfr[4];
    #pragma unroll
    for (int m = 0; m < 4; ++m)
      af[m] = *reinterpret_cast<const short8*>(&As[(wr << 6) + (m << 4) + l15][g << 3]);
    #pragma unroll
    for (int n = 0; n < 4; ++n)
      bfr[n] = *reinterpret_cast<const short8*>(&Bs[(wc << 6) + (n << 4) + l15][g << 3]);
    #pragma unroll
    for (int m = 0; m < 4; ++m)
      #pragma unroll
      for (int n = 0; n < 4; ++n)
        acc[m][n] = __builtin_amdgcn_mfma_f32_16x16x32_bf16(af[m], bfr[n], acc[m][n], 0, 0, 0);
    __syncthreads();
  }
  #pragma unroll
  for (int n = 0; n < 4; ++n) {
    int col = n0 + (wc << 6) + (n << 4) + l15;
    if (col >= N) continue;
    float bv = bias[col];
    #pragma unroll
    for (int m = 0; m < 4; ++m) {
      int rowb = m0 + (wr << 6) + (m << 4) + (g << 2);
      #pragma unroll
      for (int r = 0; r < 4; ++r) {
        float v = acc[m][n][r] + bv;
        if (OUT_BF16)
          reinterpret_cast<unsigned short*>(Cout)[(size_t)(rowb + r) * N + col] = f2bf(v);
        else
          reinterpret_cast<float*>(Cout)[(size_t)(rowb + r) * N + col] = v;
      }
    }
  }
}

// ---------------- fused causal flash attention ----------------
// grid: (B*NH, S/64). block: 256 (4 waves, each 16 q-rows).
// q_raw: (B*S, 3072)  cols [0,2048) = q_c (h*128+d), [2048,3072) = q_r raw (h*64+j)
// kv_raw: (B*S, 4096) cols h*256+d : d<128 k_c, d>=128 v
// krro: (B*S, 64) rope'd shared k_r;  attn_out: (B*S, 2048) col h*128+v
__global__ __launch_bounds__(256) void k_mla_attn(
    const unsigned short* __restrict__ q_raw, const unsigned short* __restrict__ kv_raw,
    const unsigned short* __restrict__ krro, const float* __restrict__ tab,
    unsigned short* __restrict__ attn_out) {
  __shared__ __align__(16) unsigned short Vt[128][40];  // V^T tile: [vcol][kv]
  const int tid = threadIdx.x;
  const int lane = tid & 63, w = tid >> 6;
  const int l15 = lane & 15, g = lane >> 4;
  const int bh = blockIdx.x, b = bh >> 4, h = bh & 15;
  const int qt = blockIdx.y;
  const int q0 = (qt << 6) + (w << 4);
  const int srow = q0 + l15;                    // this lane's q sequence pos
  const size_t qoff = ((size_t)b * S_LEN + srow) * 3072;

  // hoist Q fragments (B-operand: lane holds Q[row=l15][k=8g+e]), rope inline on d>=128
  short8 qf[6];
  #pragma unroll
  for (int d = 0; d < 4; ++d)
    qf[d] = *reinterpret_cast<const short8*>(&q_raw[qoff + h * 128 + d * 32 + g * 8]);
  #pragma unroll
  for (int d = 0; d < 2; ++d) {
    short8 rv = *reinterpret_cast<const short8*>(&q_raw[qoff + 2048 + h * 64 + d * 32 + g * 8]);
    int p0 = d * 16 + g * 4;
    union { unsigned short us[8]; short8 v; } u;
    #pragma unroll
    for (int pi = 0; pi < 4; ++pi) {
      float c = tab[(srow * 32 + p0 + pi) * 2];
      float sn = tab[(srow * 32 + p0 + pi) * 2 + 1];
      float x1 = bf2f((unsigned short)rv[2 * pi]);
      float x2 = bf2f((unsigned short)rv[2 * pi + 1]);
      u.us[2 * pi] = f2bf(x1 * c - x2 * sn);
      u.us[2 * pi + 1] = f2bf(x1 * sn + x2 * c);
    }
    qf[4 + d] = u.v;
  }

  f32x4 acc[8];
  #pragma unroll
  for (int i = 0; i < 8; ++i) acc[i] = f32x4{0.f, 0.f, 0.f, 0.f};
  float mrun = -1e30f, lsum = 0.f;
  const int nt_block = (qt << 1) + 2;
  const int nt_w = (q0 + 47) >> 5;
  const size_t bsb = (size_t)b * S_LEN;

  for (int t = 0; t < nt_block; ++t) {
    const int kvb = t << 5;
    __syncthreads();
    // stage V^T tile (32 kv x 128 vcol) cooperatively
    #pragma unroll
    for (int i = 0; i < 2; ++i) {
      int c = tid + (i << 8);
      int kv = c & 31, cc = (c >> 5) << 3;
      int4 v = *reinterpret_cast<const int4*>(
          &kv_raw[(bsb + kvb + kv) * 4096 + h * 256 + 128 + cc]);
      const unsigned short* pv = reinterpret_cast<const unsigned short*>(&v);
      #pragma unroll
      for (int j = 0; j < 8; ++j) Vt[cc + j][kv] = pv[j];
    }
    __syncthreads();
    if (t >= nt_w) continue;

    // scores^T = K * Q^T : D[kv][q], two 16-row halves
    f32x4 sc0 = f32x4{0.f, 0.f, 0.f, 0.f}, sc1 = f32x4{0.f, 0.f, 0.f, 0.f};
    const size_t krow0 = bsb + kvb + l15;
    #pragma unroll
    for (int d = 0; d < 6; ++d) {
      short8 kf0, kf1;
      if (d < 4) {
        kf0 = *reinterpret_cast<const short8*>(&kv_raw[krow0 * 4096 + h * 256 + d * 32 + g * 8]);
        kf1 = *reinterpret_cast<const short8*>(&kv_raw[(krow0 + 16) * 4096 + h * 256 + d * 32 + g * 8]);
      } else {
        kf0 = *reinterpret_cast<const short8*>(&krro[krow0 * 64 + (d - 4) * 32 + g * 8]);
        kf1 = *reinterpret_cast<const short8*>(&krro[(krow0 + 16) * 64 + (d - 4) * 32 + g * 8]);
      }
      sc0 = __builtin_amdgcn_mfma_f32_16x16x32_bf16(kf0, qf[d], sc0, 0, 0, 0);
      sc1 = __builtin_amdgcn_mfma_f32_16x16x32_bf16(kf1, qf[d], sc1, 0, 0, 0);
    }
    // scale + causal mask; lane holds q=srow, kv = kvb + {4g+r, 16+4g+r}
    float p[8];
    float tmax = -1e30f;
    #pragma unroll
    for (int r = 0; r < 4; ++r) {
      int kv0 = kvb + (g << 2) + r;
      float s0 = sc0[r] * SCALE_F;
      if (kv0 > srow) s0 = -1e30f;
      float s1 = sc1[r] * SCALE_F;
      if (kv0 + 16 > srow) s1 = -1e30f;
      p[r] = s0; p[4 + r] = s1;
      tmax = fmaxf(tmax, fmaxf(s0, s1));
    }
    tmax = fmaxf(tmax, __shfl_xor(tmax, 16));
    tmax = fmaxf(tmax, __shfl_xor(tmax, 32));
    float mnew = fmaxf(mrun, tmax);
    float scold = __expf(mrun - mnew);
    float ts = 0.f;
    #pragma unroll
    for (int i = 0; i < 8; ++i) { p[i] = __expf(p[i] - mnew); ts += p[i]; }
    ts += __shfl_xor(ts, 16);
    ts += __shfl_xor(ts, 32);
    lsum = lsum * scold + ts;
    mrun = mnew;

    // pack P to bf16x2 words; redistribute so lane holds P[q=l15][kv=8g+e]
    unsigned int w00 = (unsigned int)f2bf(p[0]) | ((unsigned int)f2bf(p[1]) << 16);
    unsigned int w01 = (unsigned int)f2bf(p[2]) | ((unsigned int)f2bf(p[3]) << 16);
    unsigned int w10 = (unsigned int)f2bf(p[4]) | ((unsigned int)f2bf(p[5]) << 16);
    unsigned int w11 = (unsigned int)f2bf(p[6]) | ((unsigned int)f2bf(p[7]) << 16);
    const int hsel = g >> 1;
    const int a = (g << 1) & 3;
    const int src0 = (a << 4) + l15, src1 = ((a + 1) << 4) + l15;
    unsigned int s00 = (unsigned int)__shfl((int)w00, src0);
    unsigned int s01 = (unsigned int)__shfl((int)w01, src0);
    unsigned int s10 = (unsigned int)__shfl((int)w10, src0);
    unsigned int s11 = (unsigned int)__shfl((int)w11, src0);
    unsigned int t00 = (unsigned int)__shfl((int)w00, src1);
    unsigned int t01 = (unsigned int)__shfl((int)w01, src1);
    unsigned int t10 = (unsigned int)__shfl((int)w10, src1);
    unsigned int t11 = (unsigned int)__shfl((int)w11, src1);
    union { unsigned int u[4]; short8 v; } pa;
    pa.u[0] = hsel ? s10 : s00;
    pa.u[1] = hsel ? s11 : s01;
    pa.u[2] = hsel ? t10 : t00;
    pa.u[3] = hsel ? t11 : t01;

    // rescale factors per accumulator row q = q0 + 4g + r
    float f0 = __shfl(scold, (g << 2) + 0);
    float f1 = __shfl(scold, (g << 2) + 1);
    float f2v = __shfl(scold, (g << 2) + 2);
    float f3 = __shfl(scold, (g << 2) + 3);
    f32x4 fv = f32x4{f0, f1, f2v, f3};
    #pragma unroll
    for (int vg = 0; vg < 8; ++vg) {
      acc[vg] *= fv;
      short8 vb = *reinterpret_cast<const short8*>(&Vt[(vg << 4) + l15][g << 3]);
      acc[vg] = __builtin_amdgcn_mfma_f32_16x16x32_bf16(pa.v, vb, acc[vg], 0, 0, 0);
    }
  }

  float li0 = 1.f / __shfl(lsum, (g << 2) + 0);
  float li1 = 1.f / __shfl(lsum, (g << 2) + 1);
  float li2 = 1.f / __shfl(lsum, (g << 2) + 2);
  float li3 = 1.f / __shfl(lsum, (g << 2) + 3);
  f32x4 lv = f32x4{li0, li1, li2, li3};
  const size_t obase = (size_t)b * S_LEN + q0 + (g << 2);
  #pragma unroll
  for (int vg = 0; vg < 8; ++vg) {
    f32x4 o = acc[vg] * lv;
    #pragma unroll
    for (int r = 0; r < 4; ++r)
      attn_out[(obase + r) * 2048 + h * 128 + (vg << 4) + l15] = f2bf(o[r]);
  }
}

// ---------------- launch ----------------

extern "C" void kernel_launch(void* const* d_in, const int* in_sizes, int n_in,
                              void* d_out, int out_size, void* d_ws, size_t ws_size,
                              hipStream_t stream) {
  (void)in_sizes; (void)n_in; (void)out_size; (void)ws_size;
  const float* x = (const float*)d_in[0];
  const float* freq = (const float*)d_in[1];
  // d_in[2] = mask: always causal tril -> handled analytically
  const float* w_dq = (const float*)d_in[3];
  const float* b_dq = (const float*)d_in[4];
  const float* w_uq = (const float*)d_in[5];
  const float* b_uq = (const float*)d_in[6];
  const float* w_qr = (const float*)d_in[7];
  const float* b_qr = (const float*)d_in[8];
  const float* w_dkv = (const float*)d_in[9];
  const float* b_dkv = (const float*)d_in[10];
  const float* w_ukv = (const float*)d_in[11];
  const float* b_ukv = (const float*)d_in[12];
  const float* w_kr = (const float*)d_in[13];
  const float* b_kr = (const float*)d_in[14];
  const float* w_o = (const float*)d_in[15];
  const float* b_o = (const float*)d_in[16];

  char* ws = (char*)d_ws;
  size_t off = 0;
  auto alloc = [&](size_t bytes) {
    char* p = ws + off;
    off += (bytes + 255) & ~(size_t)255;
    return p;
  };
  unsigned short* x_bf   = (unsigned short*)alloc((size_t)4096 * 2048 * 2);
  unsigned short* wdq_t  = (unsigned short*)alloc((size_t)768 * 2048 * 2);
  unsigned short* wdkv_t = (unsigned short*)alloc((size_t)512 * 2048 * 2);
  unsigned short* wkr_t  = (unsigned short*)alloc((size_t)64 * 2048 * 2);
  unsigned short* wqc_t  = (unsigned short*)alloc((size_t)3072 * 768 * 2);
  unsigned short* wukv_t = (unsigned short*)alloc((size_t)4096 * 512 * 2);
  unsigned short* wo_t   = (unsigned short*)alloc((size_t)2048 * 2048 * 2);
  float* tab             = (float*)alloc((size_t)2048 * 32 * 2 * 4);
  float* bcat            = (float*)alloc((size_t)3072 * 4);
  unsigned short* c_q    = (unsigned short*)alloc((size_t)4096 * 768 * 2);
  unsigned short* c_kv   = (unsigned short*)alloc((size_t)4096 * 512 * 2);
  unsigned short* krraw  = (unsigned short*)alloc((size_t)4096 * 64 * 2);
  unsigned short* krro   = (unsigned short*)alloc((size_t)4096 * 64 * 2);
  unsigned short* q_raw  = (unsigned short*)alloc((size_t)4096 * 3072 * 2);
  unsigned short* kv_raw = (unsigned short*)alloc((size_t)4096 * 4096 * 2);
  unsigned short* attn   = (unsigned short*)alloc((size_t)4096 * 2048 * 2);

  hipMemcpyAsync(bcat, b_uq, 2048 * sizeof(float), hipMemcpyDeviceToDevice, stream);
  hipMemcpyAsync(bcat + 2048, b_qr, 1024 * sizeof(float), hipMemcpyDeviceToDevice, stream);

  k_cast_bf16<<<dim3(8192), dim3(256), 0, stream>>>(x, x_bf, 4096 * 2048 / 4);
  k_rope_table<<<dim3(256), dim3(256), 0, stream>>>(freq, tab, 2048 * 32);

  k_transpose_cast<<<dim3(768 / 64, 2048 / 64), dim3(256), 0, stream>>>(w_dq, wdq_t, 2048, 768);
  k_transpose_cast<<<dim3(512 / 64, 2048 / 64), dim3(256), 0, stream>>>(w_dkv, wdkv_t, 2048, 512);
  k_transpose_cast<<<dim3(1, 2048 / 64), dim3(256), 0, stream>>>(w_kr, wkr_t, 2048, 64);
  k_transpose_cast<<<dim3(2048 / 64, 768 / 64), dim3(256), 0, stream>>>(w_uq, wqc_t, 768, 2048);
  k_transpose_cast<<<dim3(1024 / 64, 768 / 64), dim3(256), 0, stream>>>(
      w_qr, wqc_t + (size_t)2048 * 768, 768, 1024);
  k_transpose_cast<<<dim3(4096 / 64, 512 / 64), dim3(256), 0, stream>>>(w_ukv, wukv_t, 512, 4096);
  k_transpose_cast<<<dim3(2048 / 64, 2048 / 64), dim3(256), 0, stream>>>(w_o, wo_t, 2048, 2048);

  // down-projections from x
  k_gemm_bt<1><<<dim3(6, 32), dim3(256), 0, stream>>>(x_bf, wdq_t, b_dq, c_q, 4096, 768, 2048);
  k_gemm_bt<1><<<dim3(4, 32), dim3(256), 0, stream>>>(x_bf, wdkv_t, b_dkv, c_kv, 4096, 512, 2048);
  k_gemm_bt<1><<<dim3(1, 32), dim3(256), 0, stream>>>(x_bf, wkr_t, b_kr, krraw, 4096, 64, 2048);
  k_rope_kr<<<dim3(512), dim3(256), 0, stream>>>(krraw, tab, krro, 4096 * 32);

  // up-projections
  k_gemm_bt<1><<<dim3(24, 32), dim3(256), 0, stream>>>(c_q, wqc_t, bcat, q_raw, 4096, 3072, 768);
  k_gemm_bt<1><<<dim3(32, 32), dim3(256), 0, stream>>>(c_kv, wukv_t, b_ukv, kv_raw, 4096, 4096, 512);

  // fused causal attention (rope on q_r applied inline)
  k_mla_attn<<<dim3(32, 32), dim3(256), 0, stream>>>(q_raw, kv_raw, krro, tab, attn);

  // output projection -> f32
  k_gemm_bt<0><<<dim3(16, 32), dim3(256), 0, stream>>>(attn, wo_t, b_o, (float*)d_out, 4096, 2048, 2048);
}

// Round 2
// 505.609 us; speedup vs baseline: 1.3244x; 1.3244x over previous
//
#include <hip/hip_runtime.h>
#include <cstdint>
#include <cstddef>

#define S_LEN 2048
#define SCALE_F 0.07216878364870323f  // 1/sqrt(192)

typedef __attribute__((ext_vector_type(8))) short short8;
typedef __attribute__((ext_vector_type(4))) float f32x4;
typedef __attribute__((ext_vector_type(4))) unsigned short ushort4v;

__device__ __forceinline__ unsigned short f2bf(float f) {
  unsigned int u = __builtin_bit_cast(unsigned int, f);
  u += 0x7FFFu + ((u >> 16) & 1u);
  return (unsigned short)(u >> 16);
}
__device__ __forceinline__ float bf2f(unsigned short h) {
  unsigned int u = ((unsigned int)h) << 16;
  return __builtin_bit_cast(float, u);
}

typedef const __attribute__((address_space(1))) void* gas_ptr;
typedef __attribute__((address_space(3))) void* las_ptr;
__device__ __forceinline__ void gload16(const void* g, void* l) {
  // global -> LDS direct, 16B per lane; LDS dest = wave-uniform base + lane*16
  __builtin_amdgcn_global_load_lds((gas_ptr)g, (las_ptr)l, 16, 0, 0);
}

// ---------------- elementwise kernels ----------------

__global__ void k_cast_bf16(const float* __restrict__ src, unsigned short* __restrict__ dst, int n4) {
  int i = blockIdx.x * 256 + threadIdx.x;
  if (i >= n4) return;
  const float4 v = reinterpret_cast<const float4*>(src)[i];
  ushort4v o = { f2bf(v.x), f2bf(v.y), f2bf(v.z), f2bf(v.w) };
  reinterpret_cast<ushort4v*>(dst)[i] = o;
}

__global__ void k_rope_table(const float* __restrict__ freq, float* __restrict__ tab, int n) {
  int i = blockIdx.x * 256 + threadIdx.x;
  if (i >= n) return;
  float f = freq[i];
  tab[2 * i] = cosf(f);
  tab[2 * i + 1] = sinf(f);
}

// src: K x N f32  ->  dst: N x K bf16   (K, N multiples of 64)
__global__ __launch_bounds__(256) void k_transpose_cast(
    const float* __restrict__ src, unsigned short* __restrict__ dst, int K, int N) {
  __shared__ __align__(16) unsigned short tile[64][72];
  const int tid = threadIdx.x;
  const int kb = blockIdx.y * 64, nb = blockIdx.x * 64;
  #pragma unroll
  for (int i = 0; i < 4; ++i) {
    int idx = i * 256 + tid;
    int row = idx >> 4, c4 = (idx & 15) << 2;
    const float4 v = *reinterpret_cast<const float4*>(&src[(size_t)(kb + row) * N + nb + c4]);
    tile[row][c4 + 0] = f2bf(v.x);
    tile[row][c4 + 1] = f2bf(v.y);
    tile[row][c4 + 2] = f2bf(v.z);
    tile[row][c4 + 3] = f2bf(v.w);
  }
  __syncthreads();
  #pragma unroll
  for (int i = 0; i < 4; ++i) {
    int idx = i * 256 + tid;
    int n = idx >> 4, kc = (idx & 15) << 2;
    ushort4v o = { tile[kc + 0][n], tile[kc + 1][n], tile[kc + 2][n], tile[kc + 3][n] };
    *reinterpret_cast<ushort4v*>(&dst[(size_t)(nb + n) * K + kb + kc]) = o;
  }
}

__global__ void k_rope_kr(const unsigned short* __restrict__ raw, const float* __restrict__ tab,
                          unsigned short* __restrict__ out, int npairs) {
  int idx = blockIdx.x * 256 + threadIdx.x;
  if (idx >= npairs) return;
  int bs = idx >> 5, p = idx & 31;
  int s = bs & (S_LEN - 1);
  float c = tab[(s * 32 + p) * 2], sn = tab[(s * 32 + p) * 2 + 1];
  float x1 = bf2f(raw[bs * 64 + 2 * p]), x2 = bf2f(raw[bs * 64 + 2 * p + 1]);
  out[bs * 64 + 2 * p] = f2bf(x1 * c - x2 * sn);
  out[bs * 64 + 2 * p + 1] = f2bf(x1 * sn + x2 * c);
}

// ---------------- GEMM (m97 structure): C[M,N] = A[M,K] * Bt[N,K]^T + bias ----------------
// 128x128 tile, BK=32, linear LDS, global_load_lds width-16 staging.
template <int OUT_BF16>
__global__ __launch_bounds__(256) void k_gemm_bt(
    const unsigned short* __restrict__ A, const unsigned short* __restrict__ Bt,
    const float* __restrict__ bias, void* __restrict__ Cout, int M, int N, int K) {
  __shared__ __align__(16) unsigned short As[128 * 32];
  __shared__ __align__(16) unsigned short Bs[128 * 32];
  const int tid = threadIdx.x;
  const int lane = tid & 63, wid = tid >> 6;
  const int wr = wid >> 1, wc = wid & 1;
  const int m0 = blockIdx.y << 7, n0 = blockIdx.x << 7;
  const int l15 = lane & 15, g = lane >> 4;

  // staging geometry: wave wid covers rows [wid*32, wid*32+32) in two 16-row chunks
  const int srow = (wid << 5) + (lane >> 2);   // chunk 0 row
  const int scol = (lane & 3) << 3;            // element col (8 bf16 = 16B)
  const unsigned short* aptr0 = &A[(size_t)(m0 + srow) * K + scol];
  const unsigned short* aptr1 = &A[(size_t)(m0 + srow + 16) * K + scol];
  int br0 = n0 + srow;      if (br0 >= N) br0 = N - 1;
  int br1 = n0 + srow + 16; if (br1 >= N) br1 = N - 1;
  const unsigned short* bptr0 = &Bt[(size_t)br0 * K + scol];
  const unsigned short* bptr1 = &Bt[(size_t)br1 * K + scol];
  unsigned short* lA0 = &As[((wid << 1) + 0) << 9];  // wave-uniform 1KB chunks
  unsigned short* lA1 = &As[((wid << 1) + 1) << 9];
  unsigned short* lB0 = &Bs[((wid << 1) + 0) << 9];
  unsigned short* lB1 = &Bs[((wid << 1) + 1) << 9];

  f32x4 acc[4][4];
  #pragma unroll
  for (int m = 0; m < 4; ++m)
    #pragma unroll
    for (int n = 0; n < 4; ++n) acc[m][n] = f32x4{0.f, 0.f, 0.f, 0.f};

  for (int k0 = 0; k0 < K; k0 += 32) {
    gload16(aptr0 + k0, lA0);
    gload16(aptr1 + k0, lA1);
    gload16(bptr0 + k0, lB0);
    gload16(bptr1 + k0, lB1);
    __syncthreads();
    short8 af[4], bfr[4];
    #pragma unroll
    for (int m = 0; m < 4; ++m)
      af[m] = *reinterpret_cast<const short8*>(&As[(((wr << 6) + (m << 4) + l15) << 5) + (g << 3)]);
    #pragma unroll
    for (int n = 0; n < 4; ++n)
      bfr[n] = *reinterpret_cast<const short8*>(&Bs[(((wc << 6) + (n << 4) + l15) << 5) + (g << 3)]);
    __builtin_amdgcn_s_setprio(1);
    #pragma unroll
    for (int m = 0; m < 4; ++m)
      #pragma unroll
      for (int n = 0; n < 4; ++n)
        acc[m][n] = __builtin_amdgcn_mfma_f32_16x16x32_bf16(af[m], bfr[n], acc[m][n], 0, 0, 0);
    __builtin_amdgcn_s_setprio(0);
    __syncthreads();
  }
  #pragma unroll
  for (int n = 0; n < 4; ++n) {
    int col = n0 + (wc << 6) + (n << 4) + l15;
    if (col >= N) continue;
    float bv = bias[col];
    #pragma unroll
    for (int m = 0; m < 4; ++m) {
      int rowb = m0 + (wr << 6) + (m << 4) + (g << 2);
      #pragma unroll
      for (int r = 0; r < 4; ++r) {
        float v = acc[m][n][r] + bv;
        if (OUT_BF16)
          reinterpret_cast<unsigned short*>(Cout)[(size_t)(rowb + r) * N + col] = f2bf(v);
        else
          reinterpret_cast<float*>(Cout)[(size_t)(rowb + r) * N + col] = v;
      }
    }
  }
}

// ---------------- fused causal flash attention ----------------
// grid: (B*NH, 16). block: 256 (4 waves, each 16 q-rows).
// Each block processes the balanced q-tile pair {p, 31-p}: 66 KV tiles total.
__global__ __launch_bounds__(256) void k_mla_attn(
    const unsigned short* __restrict__ q_raw, const unsigned short* __restrict__ kv_raw,
    const unsigned short* __restrict__ krro, const float* __restrict__ tab,
    unsigned short* __restrict__ attn_out) {
  __shared__ __align__(16) unsigned short Vt[128][40];  // V^T tile: [vcol][kv]
  const int tid = threadIdx.x;
  const int lane = tid & 63, w = tid >> 6;
  const int l15 = lane & 15, g = lane >> 4;
  const int bh = blockIdx.x, b = bh >> 4, h = bh & 15;
  const size_t bsb = (size_t)b * S_LEN;
  const int p = blockIdx.y;

  // this thread's V staging slot (two 16B pieces per 32x128 tile)
  const int vkv = tid & 31;
  const int vcc = (tid >> 5) << 3;  // 0..56; second piece at +64

  for (int half = 0; half < 2; ++half) {
    const int qt = half ? (31 - p) : p;
    const int q0 = (qt << 6) + (w << 4);
    const int srow = q0 + l15;
    const size_t qoff = (bsb + srow) * 3072;

    // hoist Q fragments (B-operand: lane holds Q[row=l15][k=8g+e]), rope inline on d>=128
    short8 qf[6];
    #pragma unroll
    for (int d = 0; d < 4; ++d)
      qf[d] = *reinterpret_cast<const short8*>(&q_raw[qoff + h * 128 + d * 32 + g * 8]);
    #pragma unroll
    for (int d = 0; d < 2; ++d) {
      short8 rv = *reinterpret_cast<const short8*>(&q_raw[qoff + 2048 + h * 64 + d * 32 + g * 8]);
      int p0 = d * 16 + g * 4;
      union { unsigned short us[8]; short8 v; } u;
      #pragma unroll
      for (int pi = 0; pi < 4; ++pi) {
        float c = tab[(srow * 32 + p0 + pi) * 2];
        float sn = tab[(srow * 32 + p0 + pi) * 2 + 1];
        float x1 = bf2f((unsigned short)rv[2 * pi]);
        float x2 = bf2f((unsigned short)rv[2 * pi + 1]);
        u.us[2 * pi] = f2bf(x1 * c - x2 * sn);
        u.us[2 * pi + 1] = f2bf(x1 * sn + x2 * c);
      }
      qf[4 + d] = u.v;
    }

    f32x4 acc[8];
    #pragma unroll
    for (int i = 0; i < 8; ++i) acc[i] = f32x4{0.f, 0.f, 0.f, 0.f};
    float mrun = -1e30f, lsum = 0.f;
    const int nt_block = (qt << 1) + 2;
    const int nt_w = (q0 + 47) >> 5;

    // prefetch V tile 0 of this half into registers
    int4 vra = *reinterpret_cast<const int4*>(&kv_raw[(bsb + vkv) * 4096 + h * 256 + 128 + vcc]);
    int4 vrb = *reinterpret_cast<const int4*>(&kv_raw[(bsb + vkv) * 4096 + h * 256 + 192 + vcc]);

    for (int t = 0; t < nt_block; ++t) {
      const int kvb = t << 5;
      __syncthreads();  // prior tile's Vt reads (or prior half) complete
      {
        const unsigned short* pa = reinterpret_cast<const unsigned short*>(&vra);
        const unsigned short* pb = reinterpret_cast<const unsigned short*>(&vrb);
        #pragma unroll
        for (int j = 0; j < 8; ++j) Vt[vcc + j][vkv] = pa[j];
        #pragma unroll
        for (int j = 0; j < 8; ++j) Vt[vcc + 64 + j][vkv] = pb[j];
      }
      __syncthreads();
      // issue next tile's V loads now; latency hides under this tile's compute
      if (t + 1 < nt_block) {
        vra = *reinterpret_cast<const int4*>(
            &kv_raw[(bsb + kvb + 32 + vkv) * 4096 + h * 256 + 128 + vcc]);
        vrb = *reinterpret_cast<const int4*>(
            &kv_raw[(bsb + kvb + 32 + vkv) * 4096 + h * 256 + 192 + vcc]);
      }
      if (t >= nt_w) continue;

      // scores^T = K * Q^T : D[kv][q], two 16-row halves
      f32x4 sc0 = f32x4{0.f, 0.f, 0.f, 0.f}, sc1 = f32x4{0.f, 0.f, 0.f, 0.f};
      const size_t krow0 = bsb + kvb + l15;
      short8 kf0[6], kf1[6];
      #pragma unroll
      for (int d = 0; d < 4; ++d) {
        kf0[d] = *reinterpret_cast<const short8*>(&kv_raw[krow0 * 4096 + h * 256 + d * 32 + g * 8]);
        kf1[d] = *reinterpret_cast<const short8*>(&kv_raw[(krow0 + 16) * 4096 + h * 256 + d * 32 + g * 8]);
      }
      #pragma unroll
      for (int d = 0; d < 2; ++d) {
        kf0[4 + d] = *reinterpret_cast<const short8*>(&krro[krow0 * 64 + d * 32 + g * 8]);
        kf1[4 + d] = *reinterpret_cast<const short8*>(&krro[(krow0 + 16) * 64 + d * 32 + g * 8]);
      }
      __builtin_amdgcn_s_setprio(1);
      #pragma unroll
      for (int d = 0; d < 6; ++d) {
        sc0 = __builtin_amdgcn_mfma_f32_16x16x32_bf16(kf0[d], qf[d], sc0, 0, 0, 0);
        sc1 = __builtin_amdgcn_mfma_f32_16x16x32_bf16(kf1[d], qf[d], sc1, 0, 0, 0);
      }
      __builtin_amdgcn_s_setprio(0);

      // scale + causal mask; lane holds q=srow, kv = kvb + {4g+r, 16+4g+r}
      float pv[8];
      float tmax = -1e30f;
      #pragma unroll
      for (int r = 0; r < 4; ++r) {
        int kv0 = kvb + (g << 2) + r;
        float s0 = sc0[r] * SCALE_F;
        if (kv0 > srow) s0 = -1e30f;
        float s1 = sc1[r] * SCALE_F;
        if (kv0 + 16 > srow) s1 = -1e30f;
        pv[r] = s0; pv[4 + r] = s1;
        tmax = fmaxf(tmax, fmaxf(s0, s1));
      }
      tmax = fmaxf(tmax, __shfl_xor(tmax, 16));
      tmax = fmaxf(tmax, __shfl_xor(tmax, 32));
      float mnew = fmaxf(mrun, tmax);
      float scold = __expf(mrun - mnew);
      float ts = 0.f;
      #pragma unroll
      for (int i = 0; i < 8; ++i) { pv[i] = __expf(pv[i] - mnew); ts += pv[i]; }
      ts += __shfl_xor(ts, 16);
      ts += __shfl_xor(ts, 32);
      lsum = lsum * scold + ts;
      mrun = mnew;

      // pack P to bf16x2 words; redistribute so lane holds P[q=l15][kv=8g+e]
      unsigned int w00 = (unsigned int)f2bf(pv[0]) | ((unsigned int)f2bf(pv[1]) << 16);
      unsigned int w01 = (unsigned int)f2bf(pv[2]) | ((unsigned int)f2bf(pv[3]) << 16);
      unsigned int w10 = (unsigned int)f2bf(pv[4]) | ((unsigned int)f2bf(pv[5]) << 16);
      unsigned int w11 = (unsigned int)f2bf(pv[6]) | ((unsigned int)f2bf(pv[7]) << 16);
      const int hsel = g >> 1;
      const int a = (g << 1) & 3;
      const int src0 = (a << 4) + l15, src1 = ((a + 1) << 4) + l15;
      unsigned int s00 = (unsigned int)__shfl((int)w00, src0);
      unsigned int s01 = (unsigned int)__shfl((int)w01, src0);
      unsigned int s10 = (unsigned int)__shfl((int)w10, src0);
      unsigned int s11 = (unsigned int)__shfl((int)w11, src0);
      unsigned int t00 = (unsigned int)__shfl((int)w00, src1);
      unsigned int t01 = (unsigned int)__shfl((int)w01, src1);
      unsigned int t10 = (unsigned int)__shfl((int)w10, src1);
      unsigned int t11 = (unsigned int)__shfl((int)w11, src1);
      union { unsigned int u[4]; short8 v; } pa2;
      pa2.u[0] = hsel ? s10 : s00;
      pa2.u[1] = hsel ? s11 : s01;
      pa2.u[2] = hsel ? t10 : t00;
      pa2.u[3] = hsel ? t11 : t01;

      // rescale factors per accumulator row q = q0 + 4g + r
      float f0 = __shfl(scold, (g << 2) + 0);
      float f1 = __shfl(scold, (g << 2) + 1);
      float f2v = __shfl(scold, (g << 2) + 2);
      float f3 = __shfl(scold, (g << 2) + 3);
      f32x4 fv = f32x4{f0, f1, f2v, f3};
      __builtin_amdgcn_s_setprio(1);
      #pragma unroll
      for (int vg = 0; vg < 8; ++vg) {
        acc[vg] *= fv;
        short8 vb = *reinterpret_cast<const short8*>(&Vt[(vg << 4) + l15][g << 3]);
        acc[vg] = __builtin_amdgcn_mfma_f32_16x16x32_bf16(pa2.v, vb, acc[vg], 0, 0, 0);
      }
      __builtin_amdgcn_s_setprio(0);
    }

    float li0 = 1.f / __shfl(lsum, (g << 2) + 0);
    float li1 = 1.f / __shfl(lsum, (g << 2) + 1);
    float li2 = 1.f / __shfl(lsum, (g << 2) + 2);
    float li3 = 1.f / __shfl(lsum, (g << 2) + 3);
    f32x4 lv = f32x4{li0, li1, li2, li3};
    const size_t obase = bsb + q0 + (g << 2);
    #pragma unroll
    for (int vg = 0; vg < 8; ++vg) {
      f32x4 o = acc[vg] * lv;
      #pragma unroll
      for (int r = 0; r < 4; ++r)
        attn_out[(obase + r) * 2048 + h * 128 + (vg << 4) + l15] = f2bf(o[r]);
    }
  }
}

// ---------------- launch ----------------

extern "C" void kernel_launch(void* const* d_in, const int* in_sizes, int n_in,
                              void* d_out, int out_size, void* d_ws, size_t ws_size,
                              hipStream_t stream) {
  (void)in_sizes; (void)n_in; (void)out_size; (void)ws_size;
  const float* x = (const float*)d_in[0];
  const float* freq = (const float*)d_in[1];
  // d_in[2] = mask: always causal tril -> handled analytically
  const float* w_dq = (const float*)d_in[3];
  const float* b_dq = (const float*)d_in[4];
  const float* w_uq = (const float*)d_in[5];
  const float* b_uq = (const float*)d_in[6];
  const float* w_qr = (const float*)d_in[7];
  const float* b_qr = (const float*)d_in[8];
  const float* w_dkv = (const float*)d_in[9];
  const float* b_dkv = (const float*)d_in[10];
  const float* w_ukv = (const float*)d_in[11];
  const float* b_ukv = (const float*)d_in[12];
  const float* w_kr = (const float*)d_in[13];
  const float* b_kr = (const float*)d_in[14];
  const float* w_o = (const float*)d_in[15];
  const float* b_o = (const float*)d_in[16];

  char* ws = (char*)d_ws;
  size_t off = 0;
  auto alloc = [&](size_t bytes) {
    char* p = ws + off;
    off += (bytes + 255) & ~(size_t)255;
    return p;
  };
  unsigned short* x_bf   = (unsigned short*)alloc((size_t)4096 * 2048 * 2);
  unsigned short* wdq_t  = (unsigned short*)alloc((size_t)768 * 2048 * 2);
  unsigned short* wdkv_t = (unsigned short*)alloc((size_t)512 * 2048 * 2);
  unsigned short* wkr_t  = (unsigned short*)alloc((size_t)64 * 2048 * 2);
  unsigned short* wqc_t  = (unsigned short*)alloc((size_t)3072 * 768 * 2);
  unsigned short* wukv_t = (unsigned short*)alloc((size_t)4096 * 512 * 2);
  unsigned short* wo_t   = (unsigned short*)alloc((size_t)2048 * 2048 * 2);
  float* tab             = (float*)alloc((size_t)2048 * 32 * 2 * 4);
  float* bcat            = (float*)alloc((size_t)3072 * 4);
  unsigned short* c_q    = (unsigned short*)alloc((size_t)4096 * 768 * 2);
  unsigned short* c_kv   = (unsigned short*)alloc((size_t)4096 * 512 * 2);
  unsigned short* krraw  = (unsigned short*)alloc((size_t)4096 * 64 * 2);
  unsigned short* krro   = (unsigned short*)alloc((size_t)4096 * 64 * 2);
  unsigned short* q_raw  = (unsigned short*)alloc((size_t)4096 * 3072 * 2);
  unsigned short* kv_raw = (unsigned short*)alloc((size_t)4096 * 4096 * 2);
  unsigned short* attn   = (unsigned short*)alloc((size_t)4096 * 2048 * 2);

  hipMemcpyAsync(bcat, b_uq, 2048 * sizeof(float), hipMemcpyDeviceToDevice, stream);
  hipMemcpyAsync(bcat + 2048, b_qr, 1024 * sizeof(float), hipMemcpyDeviceToDevice, stream);

  k_cast_bf16<<<dim3(8192), dim3(256), 0, stream>>>(x, x_bf, 4096 * 2048 / 4);
  k_rope_table<<<dim3(256), dim3(256), 0, stream>>>(freq, tab, 2048 * 32);

  k_transpose_cast<<<dim3(768 / 64, 2048 / 64), dim3(256), 0, stream>>>(w_dq, wdq_t, 2048, 768);
  k_transpose_cast<<<dim3(512 / 64, 2048 / 64), dim3(256), 0, stream>>>(w_dkv, wdkv_t, 2048, 512);
  k_transpose_cast<<<dim3(1, 2048 / 64), dim3(256), 0, stream>>>(w_kr, wkr_t, 2048, 64);
  k_transpose_cast<<<dim3(2048 / 64, 768 / 64), dim3(256), 0, stream>>>(w_uq, wqc_t, 768, 2048);
  k_transpose_cast<<<dim3(1024 / 64, 768 / 64), dim3(256), 0, stream>>>(
      w_qr, wqc_t + (size_t)2048 * 768, 768, 1024);
  k_transpose_cast<<<dim3(4096 / 64, 512 / 64), dim3(256), 0, stream>>>(w_ukv, wukv_t, 512, 4096);
  k_transpose_cast<<<dim3(2048 / 64, 2048 / 64), dim3(256), 0, stream>>>(w_o, wo_t, 2048, 2048);

  // down-projections from x
  k_gemm_bt<1><<<dim3(6, 32), dim3(256), 0, stream>>>(x_bf, wdq_t, b_dq, c_q, 4096, 768, 2048);
  k_gemm_bt<1><<<dim3(4, 32), dim3(256), 0, stream>>>(x_bf, wdkv_t, b_dkv, c_kv, 4096, 512, 2048);
  k_gemm_bt<1><<<dim3(1, 32), dim3(256), 0, stream>>>(x_bf, wkr_t, b_kr, krraw, 4096, 64, 2048);
  k_rope_kr<<<dim3(512), dim3(256), 0, stream>>>(krraw, tab, krro, 4096 * 32);

  // up-projections
  k_gemm_bt<1><<<dim3(24, 32), dim3(256), 0, stream>>>(c_q, wqc_t, bcat, q_raw, 4096, 3072, 768);
  k_gemm_bt<1><<<dim3(32, 32), dim3(256), 0, stream>>>(c_kv, wukv_t, b_ukv, kv_raw, 4096, 4096, 512);

  // fused causal attention (rope on q_r applied inline), balanced q-tile pairs
  k_mla_attn<<<dim3(32, 16), dim3(256), 0, stream>>>(q_raw, kv_raw, krro, tab, attn);

  // output projection -> f32
  k_gemm_bt<0><<<dim3(16, 32), dim3(256), 0, stream>>>(attn, wo_t, b_o, (float*)d_out, 4096, 2048, 2048);
}

// Round 3
// 487.605 us; speedup vs baseline: 1.3733x; 1.0369x over previous
//
#include <hip/hip_runtime.h>
#include <cstdint>
#include <cstddef>

#define S_LEN 2048
#define SCALE_F 0.07216878364870323f  // 1/sqrt(192)

typedef __attribute__((ext_vector_type(8))) short short8;
typedef __attribute__((ext_vector_type(4))) float f32x4;
typedef __attribute__((ext_vector_type(4))) unsigned short ushort4v;

__device__ __forceinline__ unsigned short f2bf(float f) {
  unsigned int u = __builtin_bit_cast(unsigned int, f);
  u += 0x7FFFu + ((u >> 16) & 1u);
  return (unsigned short)(u >> 16);
}
__device__ __forceinline__ float bf2f(unsigned short h) {
  unsigned int u = ((unsigned int)h) << 16;
  return __builtin_bit_cast(float, u);
}

typedef const __attribute__((address_space(1))) void* gas_ptr;
typedef __attribute__((address_space(3))) void* las_ptr;
__device__ __forceinline__ void gload16(const void* g, void* l) {
  // global -> LDS direct, 16B per lane; LDS dest = wave-uniform base + lane*16
  __builtin_amdgcn_global_load_lds((gas_ptr)g, (las_ptr)l, 16, 0, 0);
}

// ---------------- elementwise kernels ----------------

__global__ void k_cast_bf16(const float* __restrict__ src, unsigned short* __restrict__ dst, int n4) {
  int i = blockIdx.x * 256 + threadIdx.x;
  if (i >= n4) return;
  const float4 v = reinterpret_cast<const float4*>(src)[i];
  ushort4v o = { f2bf(v.x), f2bf(v.y), f2bf(v.z), f2bf(v.w) };
  reinterpret_cast<ushort4v*>(dst)[i] = o;
}

__global__ void k_rope_table(const float* __restrict__ freq, float* __restrict__ tab, int n) {
  int i = blockIdx.x * 256 + threadIdx.x;
  if (i >= n) return;
  float f = freq[i];
  tab[2 * i] = cosf(f);
  tab[2 * i + 1] = sinf(f);
}

// src: K x N f32  ->  dst: N x K bf16   (K, N multiples of 64)
__global__ __launch_bounds__(256) void k_transpose_cast(
    const float* __restrict__ src, unsigned short* __restrict__ dst, int K, int N) {
  __shared__ __align__(16) unsigned short tile[64][72];
  const int tid = threadIdx.x;
  const int kb = blockIdx.y * 64, nb = blockIdx.x * 64;
  #pragma unroll
  for (int i = 0; i < 4; ++i) {
    int idx = i * 256 + tid;
    int row = idx >> 4, c4 = (idx & 15) << 2;
    const float4 v = *reinterpret_cast<const float4*>(&src[(size_t)(kb + row) * N + nb + c4]);
    tile[row][c4 + 0] = f2bf(v.x);
    tile[row][c4 + 1] = f2bf(v.y);
    tile[row][c4 + 2] = f2bf(v.z);
    tile[row][c4 + 3] = f2bf(v.w);
  }
  __syncthreads();
  #pragma unroll
  for (int i = 0; i < 4; ++i) {
    int idx = i * 256 + tid;
    int n = idx >> 4, kc = (idx & 15) << 2;
    ushort4v o = { tile[kc + 0][n], tile[kc + 1][n], tile[kc + 2][n], tile[kc + 3][n] };
    *reinterpret_cast<ushort4v*>(&dst[(size_t)(nb + n) * K + kb + kc]) = o;
  }
}

__global__ void k_rope_kr(const unsigned short* __restrict__ raw, const float* __restrict__ tab,
                          unsigned short* __restrict__ out, int npairs) {
  int idx = blockIdx.x * 256 + threadIdx.x;
  if (idx >= npairs) return;
  int bs = idx >> 5, p = idx & 31;
  int s = bs & (S_LEN - 1);
  float c = tab[(s * 32 + p) * 2], sn = tab[(s * 32 + p) * 2 + 1];
  float x1 = bf2f(raw[bs * 64 + 2 * p]), x2 = bf2f(raw[bs * 64 + 2 * p + 1]);
  out[bs * 64 + 2 * p] = f2bf(x1 * c - x2 * sn);
  out[bs * 64 + 2 * p + 1] = f2bf(x1 * sn + x2 * c);
}

// ---------------- GEMM (m97 structure): C[M,N] = A[M,K] * Bt[N,K]^T + bias ----------------
template <int OUT_BF16>
__global__ __launch_bounds__(256) void k_gemm_bt(
    const unsigned short* __restrict__ A, const unsigned short* __restrict__ Bt,
    const float* __restrict__ bias, void* __restrict__ Cout, int M, int N, int K) {
  __shared__ __align__(16) unsigned short As[128 * 32];
  __shared__ __align__(16) unsigned short Bs[128 * 32];
  const int tid = threadIdx.x;
  const int lane = tid & 63, wid = tid >> 6;
  const int wr = wid >> 1, wc = wid & 1;
  const int m0 = blockIdx.y << 7, n0 = blockIdx.x << 7;
  const int l15 = lane & 15, g = lane >> 4;

  const int srow = (wid << 5) + (lane >> 2);
  const int scol = (lane & 3) << 3;
  const unsigned short* aptr0 = &A[(size_t)(m0 + srow) * K + scol];
  const unsigned short* aptr1 = &A[(size_t)(m0 + srow + 16) * K + scol];
  int br0 = n0 + srow;      if (br0 >= N) br0 = N - 1;
  int br1 = n0 + srow + 16; if (br1 >= N) br1 = N - 1;
  const unsigned short* bptr0 = &Bt[(size_t)br0 * K + scol];
  const unsigned short* bptr1 = &Bt[(size_t)br1 * K + scol];
  unsigned short* lA0 = &As[((wid << 1) + 0) << 9];
  unsigned short* lA1 = &As[((wid << 1) + 1) << 9];
  unsigned short* lB0 = &Bs[((wid << 1) + 0) << 9];
  unsigned short* lB1 = &Bs[((wid << 1) + 1) << 9];

  f32x4 acc[4][4];
  #pragma unroll
  for (int m = 0; m < 4; ++m)
    #pragma unroll
    for (int n = 0; n < 4; ++n) acc[m][n] = f32x4{0.f, 0.f, 0.f, 0.f};

  for (int k0 = 0; k0 < K; k0 += 32) {
    gload16(aptr0 + k0, lA0);
    gload16(aptr1 + k0, lA1);
    gload16(bptr0 + k0, lB0);
    gload16(bptr1 + k0, lB1);
    __syncthreads();
    short8 af[4], bfr[4];
    #pragma unroll
    for (int m = 0; m < 4; ++m)
      af[m] = *reinterpret_cast<const short8*>(&As[(((wr << 6) + (m << 4) + l15) << 5) + (g << 3)]);
    #pragma unroll
    for (int n = 0; n < 4; ++n)
      bfr[n] = *reinterpret_cast<const short8*>(&Bs[(((wc << 6) + (n << 4) + l15) << 5) + (g << 3)]);
    __builtin_amdgcn_s_setprio(1);
    #pragma unroll
    for (int m = 0; m < 4; ++m)
      #pragma unroll
      for (int n = 0; n < 4; ++n)
        acc[m][n] = __builtin_amdgcn_mfma_f32_16x16x32_bf16(af[m], bfr[n], acc[m][n], 0, 0, 0);
    __builtin_amdgcn_s_setprio(0);
    __syncthreads();
  }
  #pragma unroll
  for (int n = 0; n < 4; ++n) {
    int col = n0 + (wc << 6) + (n << 4) + l15;
    if (col >= N) continue;
    float bv = bias[col];
    #pragma unroll
    for (int m = 0; m < 4; ++m) {
      int rowb = m0 + (wr << 6) + (m << 4) + (g << 2);
      #pragma unroll
      for (int r = 0; r < 4; ++r) {
        float v = acc[m][n][r] + bv;
        if (OUT_BF16)
          reinterpret_cast<unsigned short*>(Cout)[(size_t)(rowb + r) * N + col] = f2bf(v);
        else
          reinterpret_cast<float*>(Cout)[(size_t)(rowb + r) * N + col] = v;
      }
    }
  }
}

// ---------------- fused causal flash attention ----------------
// grid (B*NH, 16), block 512 = 8 waves: 4 q-strips (s) x 2 KV-parity groups (e).
// Block handles balanced q-tile pair {p, 31-p}. Group e computes KV tiles t==e (mod 2);
// flash-merge of the two partials via LDS at the end of each half.
// K tiles: async global_load_lds, 4-buf rotation, XOR-swizzled source (conflict-free ds_read_b128).
// V tiles: reg-prefetch 2 ahead -> transposed LDS (4 bufs).
__global__ __launch_bounds__(512, 4) void k_mla_attn(
    const unsigned short* __restrict__ q_raw, const unsigned short* __restrict__ kv_raw,
    const unsigned short* __restrict__ krro, const float* __restrict__ tab,
    unsigned short* __restrict__ attn_out) {
  __shared__ __align__(16) unsigned short Ks[4][32][128];  // 32 KB
  __shared__ __align__(16) unsigned short Vt[4][128][40];  // 40 KB, [vcol][kv]
  const int tid = threadIdx.x;
  const int lane = tid & 63, w = tid >> 6;
  const int s = w & 3, e = w >> 2;
  const int l15 = lane & 15, g = lane >> 4;
  const int bh = blockIdx.x, b = bh >> 4, h = bh & 15;
  const size_t bsb = (size_t)b * S_LEN;
  const int p = blockIdx.y;

  // V staging slot: 512 threads cover 32 kv x 16 col-groups, 1 int4 each per tile
  const int vkv = tid & 31;
  const int vcc = (tid >> 5) << 3;  // 0..120

  // K staging rows for this wave (within its tile): 8*s .. 8*s+7, two instrs
  const int krb = s << 3;

  for (int half = 0; half < 2; ++half) {
    const int qt = half ? (31 - p) : p;
    const int q0 = (qt << 6) + (s << 4);
    const int srow = q0 + l15;
    const size_t qoff = (bsb + srow) * 3072;
    const int ntb = (qt << 1) + 2;       // tiles staged
    const int nt_w = (q0 + 47) >> 5;     // tiles this strip computes

    __syncthreads();  // protect staging vs previous half's merge reads

    // ---- Q fragments (B-operand), rope inline on rotary dims ----
    short8 qf[6];
    #pragma unroll
    for (int d = 0; d < 4; ++d)
      qf[d] = *reinterpret_cast<const short8*>(&q_raw[qoff + h * 128 + d * 32 + g * 8]);
    #pragma unroll
    for (int d = 0; d < 2; ++d) {
      short8 rv = *reinterpret_cast<const short8*>(&q_raw[qoff + 2048 + h * 64 + d * 32 + g * 8]);
      int p0 = d * 16 + g * 4;
      union { unsigned short us[8]; short8 v; } uq;
      #pragma unroll
      for (int pi = 0; pi < 4; ++pi) {
        float c = tab[(srow * 32 + p0 + pi) * 2];
        float sn = tab[(srow * 32 + p0 + pi) * 2 + 1];
        float x1 = bf2f((unsigned short)rv[2 * pi]);
        float x2 = bf2f((unsigned short)rv[2 * pi + 1]);
        uq.us[2 * pi] = f2bf(x1 * c - x2 * sn);
        uq.us[2 * pi + 1] = f2bf(x1 * sn + x2 * c);
      }
      qf[4 + d] = uq.v;
    }

    f32x4 acc[8];
    #pragma unroll
    for (int i = 0; i < 8; ++i) acc[i] = f32x4{0.f, 0.f, 0.f, 0.f};
    float mrun = -1e30f, lsum = 0.f;

    // ---- prologue: stage tiles 0 (waves e=0) and 1 (waves e=1) ----
    {
      const int ts = e;
      int kv0 = krb + (lane >> 4);
      int uu0 = (lane & 15) ^ (kv0 & 15);
      gload16(&kv_raw[(bsb + (ts << 5) + kv0) * 4096 + h * 256 + uu0 * 8], &Ks[ts][krb][0]);
      int kv1 = kv0 + 4;
      int uu1 = (lane & 15) ^ (kv1 & 15);
      gload16(&kv_raw[(bsb + (ts << 5) + kv1) * 4096 + h * 256 + uu1 * 8], &Ks[ts][krb + 4][0]);
      int4 vA = *reinterpret_cast<const int4*>(&kv_raw[(bsb + vkv) * 4096 + h * 256 + 128 + vcc]);
      int4 vB = *reinterpret_cast<const int4*>(&kv_raw[(bsb + 32 + vkv) * 4096 + h * 256 + 128 + vcc]);
      const unsigned short* pa = reinterpret_cast<const unsigned short*>(&vA);
      const unsigned short* pb = reinterpret_cast<const unsigned short*>(&vB);
      #pragma unroll
      for (int j = 0; j < 8; ++j) Vt[0][vcc + j][vkv] = pa[j];
      #pragma unroll
      for (int j = 0; j < 8; ++j) Vt[1][vcc + j][vkv] = pb[j];
    }
    __syncthreads();

    const int U = qt + 1;
    for (int u = 0; u < U; ++u) {
      // ---- issue prefetch for tiles 2u+2 (grp0 stage) / 2u+3 (grp1 stage) ----
      {
        int tsK = (u << 1) + 2 + e;
        if (tsK < ntb) {
          int buf = tsK & 3;
          int kv0 = krb + (lane >> 4);
          int uu0 = (lane & 15) ^ (kv0 & 15);
          gload16(&kv_raw[(bsb + (tsK << 5) + kv0) * 4096 + h * 256 + uu0 * 8], &Ks[buf][krb][0]);
          int kv1 = kv0 + 4;
          int uu1 = (lane & 15) ^ (kv1 & 15);
          gload16(&kv_raw[(bsb + (tsK << 5) + kv1) * 4096 + h * 256 + uu1 * 8], &Ks[buf][krb + 4][0]);
        }
      }
      int4 vA, vB;
      const int tA = (u << 1) + 2, tB = (u << 1) + 3;
      const bool doA = tA < ntb, doB = tB < ntb;
      if (doA) vA = *reinterpret_cast<const int4*>(
          &kv_raw[(bsb + (tA << 5) + vkv) * 4096 + h * 256 + 128 + vcc]);
      if (doB) vB = *reinterpret_cast<const int4*>(
          &kv_raw[(bsb + (tB << 5) + vkv) * 4096 + h * 256 + 128 + vcc]);

      // ---- compute my tile ----
      const int t = (u << 1) + e;
      if (t < nt_w) {
        const int kvb = t << 5;
        const int kbuf = t & 3;
        const size_t krow0 = bsb + kvb + l15;
        // rotary-K fragments straight from global (small, L2-hot); issue first
        short8 kr00 = *reinterpret_cast<const short8*>(&krro[krow0 * 64 + g * 8]);
        short8 kr01 = *reinterpret_cast<const short8*>(&krro[krow0 * 64 + 32 + g * 8]);
        short8 kr10 = *reinterpret_cast<const short8*>(&krro[(krow0 + 16) * 64 + g * 8]);
        short8 kr11 = *reinterpret_cast<const short8*>(&krro[(krow0 + 16) * 64 + 32 + g * 8]);

        f32x4 sc0 = f32x4{0.f, 0.f, 0.f, 0.f}, sc1 = f32x4{0.f, 0.f, 0.f, 0.f};
        __builtin_amdgcn_s_setprio(1);
        #pragma unroll
        for (int d = 0; d < 4; ++d) {
          short8 kf0 = *reinterpret_cast<const short8*>(
              &Ks[kbuf][l15][(((d << 2) + g) ^ l15) << 3]);
          short8 kf1 = *reinterpret_cast<const short8*>(
              &Ks[kbuf][16 + l15][(((d << 2) + g) ^ l15) << 3]);
          sc0 = __builtin_amdgcn_mfma_f32_16x16x32_bf16(kf0, qf[d], sc0, 0, 0, 0);
          sc1 = __builtin_amdgcn_mfma_f32_16x16x32_bf16(kf1, qf[d], sc1, 0, 0, 0);
        }
        sc0 = __builtin_amdgcn_mfma_f32_16x16x32_bf16(kr00, qf[4], sc0, 0, 0, 0);
        sc1 = __builtin_amdgcn_mfma_f32_16x16x32_bf16(kr10, qf[4], sc1, 0, 0, 0);
        sc0 = __builtin_amdgcn_mfma_f32_16x16x32_bf16(kr01, qf[5], sc0, 0, 0, 0);
        sc1 = __builtin_amdgcn_mfma_f32_16x16x32_bf16(kr11, qf[5], sc1, 0, 0, 0);
        __builtin_amdgcn_s_setprio(0);

        // scale + causal mask; lane holds q=srow, kv = kvb + {4g+r, 16+4g+r}
        float pp[8];
        float tmax = -1e30f;
        #pragma unroll
        for (int r = 0; r < 4; ++r) {
          int kv0i = kvb + (g << 2) + r;
          float s0 = sc0[r] * SCALE_F;
          if (kv0i > srow) s0 = -1e30f;
          float s1 = sc1[r] * SCALE_F;
          if (kv0i + 16 > srow) s1 = -1e30f;
          pp[r] = s0; pp[4 + r] = s1;
          tmax = fmaxf(tmax, fmaxf(s0, s1));
        }
        tmax = fmaxf(tmax, __shfl_xor(tmax, 16));
        tmax = fmaxf(tmax, __shfl_xor(tmax, 32));
        float mnew = fmaxf(mrun, tmax);
        float scold = __expf(mrun - mnew);
        float ts = 0.f;
        #pragma unroll
        for (int i = 0; i < 8; ++i) { pp[i] = __expf(pp[i] - mnew); ts += pp[i]; }
        ts += __shfl_xor(ts, 16);
        ts += __shfl_xor(ts, 32);
        lsum = lsum * scold + ts;
        mrun = mnew;

        // pack P to bf16x2; redistribute so lane holds P[q=l15][kv=8g+e]
        unsigned int w00 = (unsigned int)f2bf(pp[0]) | ((unsigned int)f2bf(pp[1]) << 16);
        unsigned int w01 = (unsigned int)f2bf(pp[2]) | ((unsigned int)f2bf(pp[3]) << 16);
        unsigned int w10 = (unsigned int)f2bf(pp[4]) | ((unsigned int)f2bf(pp[5]) << 16);
        unsigned int w11 = (unsigned int)f2bf(pp[6]) | ((unsigned int)f2bf(pp[7]) << 16);
        const int hsel = g >> 1;
        const int asel = (g << 1) & 3;
        const int src0 = (asel << 4) + l15, src1 = ((asel + 1) << 4) + l15;
        unsigned int s00 = (unsigned int)__shfl((int)w00, src0);
        unsigned int s01 = (unsigned int)__shfl((int)w01, src0);
        unsigned int s10 = (unsigned int)__shfl((int)w10, src0);
        unsigned int s11 = (unsigned int)__shfl((int)w11, src0);
        unsigned int t00 = (unsigned int)__shfl((int)w00, src1);
        unsigned int t01 = (unsigned int)__shfl((int)w01, src1);
        unsigned int t10 = (unsigned int)__shfl((int)w10, src1);
        unsigned int t11 = (unsigned int)__shfl((int)w11, src1);
        union { unsigned int u[4]; short8 v; } pa2;
        pa2.u[0] = hsel ? s10 : s00;
        pa2.u[1] = hsel ? s11 : s01;
        pa2.u[2] = hsel ? t10 : t00;
        pa2.u[3] = hsel ? t11 : t01;

        float f0 = __shfl(scold, (g << 2) + 0);
        float f1 = __shfl(scold, (g << 2) + 1);
        float f2v = __shfl(scold, (g << 2) + 2);
        float f3 = __shfl(scold, (g << 2) + 3);
        f32x4 fv = f32x4{f0, f1, f2v, f3};
        __builtin_amdgcn_s_setprio(1);
        #pragma unroll
        for (int vg = 0; vg < 8; ++vg) {
          acc[vg] *= fv;
          short8 vb = *reinterpret_cast<const short8*>(&Vt[kbuf][(vg << 4) + l15][g << 3]);
          acc[vg] = __builtin_amdgcn_mfma_f32_16x16x32_bf16(pa2.v, vb, acc[vg], 0, 0, 0);
        }
        __builtin_amdgcn_s_setprio(0);
      }

      // ---- write prefetched V tiles ----
      if (doA) {
        const unsigned short* pa = reinterpret_cast<const unsigned short*>(&vA);
        #pragma unroll
        for (int j = 0; j < 8; ++j) Vt[tA & 3][vcc + j][vkv] = pa[j];
      }
      if (doB) {
        const unsigned short* pb = reinterpret_cast<const unsigned short*>(&vB);
        #pragma unroll
        for (int j = 0; j < 8; ++j) Vt[tB & 3][vcc + j][vkv] = pb[j];
      }
      __syncthreads();
    }

    // ---- merge parity groups (flash merge) and write output ----
    float* Msh = reinterpret_cast<float*>(&Ks[0][0][0]);  // [4 strips][16 rows][130]
    if (e == 1) {
      #pragma unroll
      for (int vg = 0; vg < 8; ++vg)
        #pragma unroll
        for (int r = 0; r < 4; ++r)
          Msh[((s << 4) + (g << 2) + r) * 130 + (vg << 4) + l15] = acc[vg][r];
      if (g == 0) {
        Msh[((s << 4) + l15) * 130 + 128] = mrun;
        Msh[((s << 4) + l15) * 130 + 129] = lsum;
      }
    }
    __syncthreads();
    if (e == 0) {
      float m1 = Msh[((s << 4) + l15) * 130 + 128];
      float l1 = Msh[((s << 4) + l15) * 130 + 129];
      float mm = fmaxf(mrun, m1);
      float ea = __expf(mrun - mm), eb = __expf(m1 - mm);
      float linv = 1.f / (lsum * ea + l1 * eb);
      float alpha = ea * linv, beta = eb * linv;
      const size_t obase = bsb + q0 + (g << 2);
      #pragma unroll
      for (int r = 0; r < 4; ++r) {
        float ar = __shfl(alpha, (g << 2) + r);
        float br = __shfl(beta, (g << 2) + r);
        #pragma unroll
        for (int vg = 0; vg < 8; ++vg) {
          float o = acc[vg][r] * ar +
                    Msh[((s << 4) + (g << 2) + r) * 130 + (vg << 4) + l15] * br;
          attn_out[(obase + r) * 2048 + h * 128 + (vg << 4) + l15] = f2bf(o);
        }
      }
    }
  }
}

// ---------------- launch ----------------

extern "C" void kernel_launch(void* const* d_in, const int* in_sizes, int n_in,
                              void* d_out, int out_size, void* d_ws, size_t ws_size,
                              hipStream_t stream) {
  (void)in_sizes; (void)n_in; (void)out_size; (void)ws_size;
  const float* x = (const float*)d_in[0];
  const float* freq = (const float*)d_in[1];
  // d_in[2] = mask: always causal tril -> handled analytically
  const float* w_dq = (const float*)d_in[3];
  const float* b_dq = (const float*)d_in[4];
  const float* w_uq = (const float*)d_in[5];
  const float* b_uq = (const float*)d_in[6];
  const float* w_qr = (const float*)d_in[7];
  const float* b_qr = (const float*)d_in[8];
  const float* w_dkv = (const float*)d_in[9];
  const float* b_dkv = (const float*)d_in[10];
  const float* w_ukv = (const float*)d_in[11];
  const float* b_ukv = (const float*)d_in[12];
  const float* w_kr = (const float*)d_in[13];
  const float* b_kr = (const float*)d_in[14];
  const float* w_o = (const float*)d_in[15];
  const float* b_o = (const float*)d_in[16];

  char* ws = (char*)d_ws;
  size_t off = 0;
  auto alloc = [&](size_t bytes) {
    char* p = ws + off;
    off += (bytes + 255) & ~(size_t)255;
    return p;
  };
  unsigned short* x_bf   = (unsigned short*)alloc((size_t)4096 * 2048 * 2);
  unsigned short* wdq_t  = (unsigned short*)alloc((size_t)768 * 2048 * 2);
  unsigned short* wdkv_t = (unsigned short*)alloc((size_t)512 * 2048 * 2);
  unsigned short* wkr_t  = (unsigned short*)alloc((size_t)64 * 2048 * 2);
  unsigned short* wqc_t  = (unsigned short*)alloc((size_t)3072 * 768 * 2);
  unsigned short* wukv_t = (unsigned short*)alloc((size_t)4096 * 512 * 2);
  unsigned short* wo_t   = (unsigned short*)alloc((size_t)2048 * 2048 * 2);
  float* tab             = (float*)alloc((size_t)2048 * 32 * 2 * 4);
  float* bcat            = (float*)alloc((size_t)3072 * 4);
  unsigned short* c_q    = (unsigned short*)alloc((size_t)4096 * 768 * 2);
  unsigned short* c_kv   = (unsigned short*)alloc((size_t)4096 * 512 * 2);
  unsigned short* krraw  = (unsigned short*)alloc((size_t)4096 * 64 * 2);
  unsigned short* krro   = (unsigned short*)alloc((size_t)4096 * 64 * 2);
  unsigned short* q_raw  = (unsigned short*)alloc((size_t)4096 * 3072 * 2);
  unsigned short* kv_raw = (unsigned short*)alloc((size_t)4096 * 4096 * 2);
  unsigned short* attn   = (unsigned short*)alloc((size_t)4096 * 2048 * 2);

  hipMemcpyAsync(bcat, b_uq, 2048 * sizeof(float), hipMemcpyDeviceToDevice, stream);
  hipMemcpyAsync(bcat + 2048, b_qr, 1024 * sizeof(float), hipMemcpyDeviceToDevice, stream);

  k_cast_bf16<<<dim3(8192), dim3(256), 0, stream>>>(x, x_bf, 4096 * 2048 / 4);
  k_rope_table<<<dim3(256), dim3(256), 0, stream>>>(freq, tab, 2048 * 32);

  k_transpose_cast<<<dim3(768 / 64, 2048 / 64), dim3(256), 0, stream>>>(w_dq, wdq_t, 2048, 768);
  k_transpose_cast<<<dim3(512 / 64, 2048 / 64), dim3(256), 0, stream>>>(w_dkv, wdkv_t, 2048, 512);
  k_transpose_cast<<<dim3(1, 2048 / 64), dim3(256), 0, stream>>>(w_kr, wkr_t, 2048, 64);
  k_transpose_cast<<<dim3(2048 / 64, 768 / 64), dim3(256), 0, stream>>>(w_uq, wqc_t, 768, 2048);
  k_transpose_cast<<<dim3(1024 / 64, 768 / 64), dim3(256), 0, stream>>>(
      w_qr, wqc_t + (size_t)2048 * 768, 768, 1024);
  k_transpose_cast<<<dim3(4096 / 64, 512 / 64), dim3(256), 0, stream>>>(w_ukv, wukv_t, 512, 4096);
  k_transpose_cast<<<dim3(2048 / 64, 2048 / 64), dim3(256), 0, stream>>>(w_o, wo_t, 2048, 2048);

  // down-projections from x
  k_gemm_bt<1><<<dim3(6, 32), dim3(256), 0, stream>>>(x_bf, wdq_t, b_dq, c_q, 4096, 768, 2048);
  k_gemm_bt<1><<<dim3(4, 32), dim3(256), 0, stream>>>(x_bf, wdkv_t, b_dkv, c_kv, 4096, 512, 2048);
  k_gemm_bt<1><<<dim3(1, 32), dim3(256), 0, stream>>>(x_bf, wkr_t, b_kr, krraw, 4096, 64, 2048);
  k_rope_kr<<<dim3(512), dim3(256), 0, stream>>>(krraw, tab, krro, 4096 * 32);

  // up-projections
  k_gemm_bt<1><<<dim3(24, 32), dim3(256), 0, stream>>>(c_q, wqc_t, bcat, q_raw, 4096, 3072, 768);
  k_gemm_bt<1><<<dim3(32, 32), dim3(256), 0, stream>>>(c_kv, wukv_t, b_ukv, kv_raw, 4096, 4096, 512);

  // fused causal attention: 512-thread blocks, KV-parity split + flash merge
  k_mla_attn<<<dim3(32, 16), dim3(512), 0, stream>>>(q_raw, kv_raw, krro, tab, attn);

  // output projection -> f32
  k_gemm_bt<0><<<dim3(16, 32), dim3(256), 0, stream>>>(attn, wo_t, b_o, (float*)d_out, 4096, 2048, 2048);
}

// Round 4
// 403.183 us; speedup vs baseline: 1.6609x; 1.2094x over previous
//
#include <hip/hip_runtime.h>
#include <cstdint>
#include <cstddef>

#define S_LEN 2048
#define SCALE_F 0.07216878364870323f  // 1/sqrt(192)

typedef __attribute__((ext_vector_type(8))) short short8;
typedef __attribute__((ext_vector_type(4))) float f32x4;
typedef __attribute__((ext_vector_type(4))) unsigned short ushort4v;

__device__ __forceinline__ unsigned short f2bf(float f) {
  unsigned int u = __builtin_bit_cast(unsigned int, f);
  u += 0x7FFFu + ((u >> 16) & 1u);
  return (unsigned short)(u >> 16);
}
__device__ __forceinline__ float bf2f(unsigned short h) {
  unsigned int u = ((unsigned int)h) << 16;
  return __builtin_bit_cast(float, u);
}

typedef const __attribute__((address_space(1))) void* gas_ptr;
typedef __attribute__((address_space(3))) void* las_ptr;
__device__ __forceinline__ void gload16(const void* g, void* l) {
  __builtin_amdgcn_global_load_lds((gas_ptr)g, (las_ptr)l, 16, 0, 0);
}

// ---------------- elementwise kernels ----------------

__global__ void k_cast_bf16(const float* __restrict__ src, unsigned short* __restrict__ dst, int n4) {
  int i = blockIdx.x * 256 + threadIdx.x;
  if (i >= n4) return;
  const float4 v = reinterpret_cast<const float4*>(src)[i];
  ushort4v o = { f2bf(v.x), f2bf(v.y), f2bf(v.z), f2bf(v.w) };
  reinterpret_cast<ushort4v*>(dst)[i] = o;
}

__global__ void k_rope_table(const float* __restrict__ freq, float* __restrict__ tab, int n) {
  int i = blockIdx.x * 256 + threadIdx.x;
  if (i >= n) return;
  float f = freq[i];
  tab[2 * i] = cosf(f);
  tab[2 * i + 1] = sinf(f);
}

// src: K x N f32  ->  dst: N x K bf16   (K, N multiples of 64)
__global__ __launch_bounds__(256) void k_transpose_cast(
    const float* __restrict__ src, unsigned short* __restrict__ dst, int K, int N) {
  __shared__ __align__(16) unsigned short tile[64][72];
  const int tid = threadIdx.x;
  const int kb = blockIdx.y * 64, nb = blockIdx.x * 64;
  #pragma unroll
  for (int i = 0; i < 4; ++i) {
    int idx = i * 256 + tid;
    int row = idx >> 4, c4 = (idx & 15) << 2;
    const float4 v = *reinterpret_cast<const float4*>(&src[(size_t)(kb + row) * N + nb + c4]);
    tile[row][c4 + 0] = f2bf(v.x);
    tile[row][c4 + 1] = f2bf(v.y);
    tile[row][c4 + 2] = f2bf(v.z);
    tile[row][c4 + 3] = f2bf(v.w);
  }
  __syncthreads();
  #pragma unroll
  for (int i = 0; i < 4; ++i) {
    int idx = i * 256 + tid;
    int n = idx >> 4, kc = (idx & 15) << 2;
    ushort4v o = { tile[kc + 0][n], tile[kc + 1][n], tile[kc + 2][n], tile[kc + 3][n] };
    *reinterpret_cast<ushort4v*>(&dst[(size_t)(nb + n) * K + kb + kc]) = o;
  }
}

// rope k_r in place from strided source (tail columns of merged down-proj output)
__global__ void k_rope_kr(const unsigned short* __restrict__ src, int src_stride,
                          const float* __restrict__ tab,
                          unsigned short* __restrict__ out, int npairs) {
  int idx = blockIdx.x * 256 + threadIdx.x;
  if (idx >= npairs) return;
  int bs = idx >> 5, p = idx & 31;
  int s = bs & (S_LEN - 1);
  float c = tab[(s * 32 + p) * 2], sn = tab[(s * 32 + p) * 2 + 1];
  float x1 = bf2f(src[(size_t)bs * src_stride + 2 * p]);
  float x2 = bf2f(src[(size_t)bs * src_stride + 2 * p + 1]);
  out[bs * 64 + 2 * p] = f2bf(x1 * c - x2 * sn);
  out[bs * 64 + 2 * p + 1] = f2bf(x1 * sn + x2 * c);
}

// ---------------- GEMM (m97 structure): C[M,N] = A[M,K] * Bt[N,K]^T + bias ----------------
template <int OUT_BF16>
__global__ __launch_bounds__(256) void k_gemm_bt(
    const unsigned short* __restrict__ A, const unsigned short* __restrict__ Bt,
    const float* __restrict__ bias, void* __restrict__ Cout, int M, int N, int K,
    int lda, int ldc) {
  __shared__ __align__(16) unsigned short As[128 * 32];
  __shared__ __align__(16) unsigned short Bs[128 * 32];
  const int tid = threadIdx.x;
  const int lane = tid & 63, wid = tid >> 6;
  const int wr = wid >> 1, wc = wid & 1;
  const int m0 = blockIdx.y << 7, n0 = blockIdx.x << 7;
  const int l15 = lane & 15, g = lane >> 4;

  const int srow = (wid << 5) + (lane >> 2);
  const int scol = (lane & 3) << 3;
  const unsigned short* aptr0 = &A[(size_t)(m0 + srow) * lda + scol];
  const unsigned short* aptr1 = &A[(size_t)(m0 + srow + 16) * lda + scol];
  int br0 = n0 + srow;      if (br0 >= N) br0 = N - 1;
  int br1 = n0 + srow + 16; if (br1 >= N) br1 = N - 1;
  const unsigned short* bptr0 = &Bt[(size_t)br0 * K + scol];
  const unsigned short* bptr1 = &Bt[(size_t)br1 * K + scol];
  unsigned short* lA0 = &As[((wid << 1) + 0) << 9];
  unsigned short* lA1 = &As[((wid << 1) + 1) << 9];
  unsigned short* lB0 = &Bs[((wid << 1) + 0) << 9];
  unsigned short* lB1 = &Bs[((wid << 1) + 1) << 9];

  f32x4 acc[4][4];
  #pragma unroll
  for (int m = 0; m < 4; ++m)
    #pragma unroll
    for (int n = 0; n < 4; ++n) acc[m][n] = f32x4{0.f, 0.f, 0.f, 0.f};

  for (int k0 = 0; k0 < K; k0 += 32) {
    gload16(aptr0 + k0, lA0);
    gload16(aptr1 + k0, lA1);
    gload16(bptr0 + k0, lB0);
    gload16(bptr1 + k0, lB1);
    __syncthreads();
    short8 af[4], bfr[4];
    #pragma unroll
    for (int m = 0; m < 4; ++m)
      af[m] = *reinterpret_cast<const short8*>(&As[(((wr << 6) + (m << 4) + l15) << 5) + (g << 3)]);
    #pragma unroll
    for (int n = 0; n < 4; ++n)
      bfr[n] = *reinterpret_cast<const short8*>(&Bs[(((wc << 6) + (n << 4) + l15) << 5) + (g << 3)]);
    __builtin_amdgcn_s_setprio(1);
    #pragma unroll
    for (int m = 0; m < 4; ++m)
      #pragma unroll
      for (int n = 0; n < 4; ++n)
        acc[m][n] = __builtin_amdgcn_mfma_f32_16x16x32_bf16(af[m], bfr[n], acc[m][n], 0, 0, 0);
    __builtin_amdgcn_s_setprio(0);
    __syncthreads();
  }
  #pragma unroll
  for (int n = 0; n < 4; ++n) {
    int col = n0 + (wc << 6) + (n << 4) + l15;
    if (col >= N) continue;
    float bv = bias[col];
    #pragma unroll
    for (int m = 0; m < 4; ++m) {
      int rowb = m0 + (wr << 6) + (m << 4) + (g << 2);
      #pragma unroll
      for (int r = 0; r < 4; ++r) {
        float v = acc[m][n][r] + bv;
        if (OUT_BF16)
          reinterpret_cast<unsigned short*>(Cout)[(size_t)(rowb + r) * ldc + col] = f2bf(v);
        else
          reinterpret_cast<float*>(Cout)[(size_t)(rowb + r) * ldc + col] = v;
      }
    }
  }
}

// ---------------- fused causal flash attention ----------------
// grid (B*NH, 16), block 512 = 8 waves: 4 q-strips (s) x 2 KV-parity groups (e).
// O^T-swapped PV: acc = O^T[vcol][q], q lane-local -> rescale/normalize without shfl.
// Defer-max (T13, THR=8): skip acc rescale when tile max grows <= 8.
__global__ __launch_bounds__(512, 4) void k_mla_attn(
    const unsigned short* __restrict__ q_raw, const unsigned short* __restrict__ kv_raw,
    const unsigned short* __restrict__ krro, const float* __restrict__ tab,
    unsigned short* __restrict__ attn_out) {
  __shared__ __align__(16) unsigned char smem[73728];
  auto Ks = reinterpret_cast<unsigned short (*)[32][128]>(smem);            // [4][32][128] 32KB
  auto Vt = reinterpret_cast<unsigned short (*)[128][40]>(smem + 32768);    // [4][128][40] 40KB
  float* Msh = reinterpret_cast<float*>(smem);  // merge scratch: 4*128*17 + 4*16*2 f32 = 35328B

  const int tid = threadIdx.x;
  const int lane = tid & 63, w = tid >> 6;
  const int s = w & 3, e = w >> 2;
  const int l15 = lane & 15, g = lane >> 4;
  const int bh = blockIdx.x, b = bh >> 4, h = bh & 15;
  const size_t bsb = (size_t)b * S_LEN;
  const int p = blockIdx.y;

  const int vkv = tid & 31;
  const int vcc = (tid >> 5) << 3;  // 0..120
  const int krb = s << 3;

  for (int half = 0; half < 2; ++half) {
    const int qt = half ? (31 - p) : p;
    const int q0 = (qt << 6) + (s << 4);
    const int srow = q0 + l15;
    const size_t qoff = (bsb + srow) * 3072;
    const int ntb = (qt << 1) + 2;
    const int nt_w = (q0 + 47) >> 5;

    __syncthreads();  // staging vs previous half's merge reads

    // ---- Q fragments (B-operand), rope inline on rotary dims ----
    short8 qf[6];
    #pragma unroll
    for (int d = 0; d < 4; ++d)
      qf[d] = *reinterpret_cast<const short8*>(&q_raw[qoff + h * 128 + d * 32 + g * 8]);
    #pragma unroll
    for (int d = 0; d < 2; ++d) {
      short8 rv = *reinterpret_cast<const short8*>(&q_raw[qoff + 2048 + h * 64 + d * 32 + g * 8]);
      int p0 = d * 16 + g * 4;
      union { unsigned short us[8]; short8 v; } uq;
      #pragma unroll
      for (int pi = 0; pi < 4; ++pi) {
        float c = tab[(srow * 32 + p0 + pi) * 2];
        float sn = tab[(srow * 32 + p0 + pi) * 2 + 1];
        float x1 = bf2f((unsigned short)rv[2 * pi]);
        float x2 = bf2f((unsigned short)rv[2 * pi + 1]);
        uq.us[2 * pi] = f2bf(x1 * c - x2 * sn);
        uq.us[2 * pi + 1] = f2bf(x1 * sn + x2 * c);
      }
      qf[4 + d] = uq.v;
    }

    f32x4 acc[8];
    #pragma unroll
    for (int i = 0; i < 8; ++i) acc[i] = f32x4{0.f, 0.f, 0.f, 0.f};
    float mrun = -1e30f, lsum = 0.f;

    // ---- prologue: stage tiles 0 (waves e=0) and 1 (waves e=1) ----
    {
      const int ts = e;
      int kv0 = krb + (lane >> 4);
      int uu0 = (lane & 15) ^ (kv0 & 15);
      gload16(&kv_raw[(bsb + (ts << 5) + kv0) * 4096 + h * 256 + uu0 * 8], &Ks[ts][krb][0]);
      int kv1 = kv0 + 4;
      int uu1 = (lane & 15) ^ (kv1 & 15);
      gload16(&kv_raw[(bsb + (ts << 5) + kv1) * 4096 + h * 256 + uu1 * 8], &Ks[ts][krb + 4][0]);
      int4 vA = *reinterpret_cast<const int4*>(&kv_raw[(bsb + vkv) * 4096 + h * 256 + 128 + vcc]);
      int4 vB = *reinterpret_cast<const int4*>(&kv_raw[(bsb + 32 + vkv) * 4096 + h * 256 + 128 + vcc]);
      const unsigned short* pa = reinterpret_cast<const unsigned short*>(&vA);
      const unsigned short* pb = reinterpret_cast<const unsigned short*>(&vB);
      #pragma unroll
      for (int j = 0; j < 8; ++j) Vt[0][vcc + j][vkv] = pa[j];
      #pragma unroll
      for (int j = 0; j < 8; ++j) Vt[1][vcc + j][vkv] = pb[j];
    }
    __syncthreads();

    const int U = qt + 1;
    for (int u = 0; u < U; ++u) {
      // ---- issue K prefetch for tile 2u+2+e ----
      {
        int tsK = (u << 1) + 2 + e;
        if (tsK < ntb) {
          int buf = tsK & 3;
          int kv0 = krb + (lane >> 4);
          int uu0 = (lane & 15) ^ (kv0 & 15);
          gload16(&kv_raw[(bsb + (tsK << 5) + kv0) * 4096 + h * 256 + uu0 * 8], &Ks[buf][krb][0]);
          int kv1 = kv0 + 4;
          int uu1 = (lane & 15) ^ (kv1 & 15);
          gload16(&kv_raw[(bsb + (tsK << 5) + kv1) * 4096 + h * 256 + uu1 * 8], &Ks[buf][krb + 4][0]);
        }
      }
      int4 vA, vB;
      const int tA = (u << 1) + 2, tB = (u << 1) + 3;
      const bool doA = tA < ntb, doB = tB < ntb;
      if (doA) vA = *reinterpret_cast<const int4*>(
          &kv_raw[(bsb + (tA << 5) + vkv) * 4096 + h * 256 + 128 + vcc]);
      if (doB) vB = *reinterpret_cast<const int4*>(
          &kv_raw[(bsb + (tB << 5) + vkv) * 4096 + h * 256 + 128 + vcc]);

      // ---- compute my tile ----
      const int t = (u << 1) + e;
      if (t < nt_w) {
        const int kvb = t << 5;
        const int kbuf = t & 3;
        const size_t krow0 = bsb + kvb + l15;
        short8 kr00 = *reinterpret_cast<const short8*>(&krro[krow0 * 64 + g * 8]);
        short8 kr01 = *reinterpret_cast<const short8*>(&krro[krow0 * 64 + 32 + g * 8]);
        short8 kr10 = *reinterpret_cast<const short8*>(&krro[(krow0 + 16) * 64 + g * 8]);
        short8 kr11 = *reinterpret_cast<const short8*>(&krro[(krow0 + 16) * 64 + 32 + g * 8]);

        f32x4 sc0 = f32x4{0.f, 0.f, 0.f, 0.f}, sc1 = f32x4{0.f, 0.f, 0.f, 0.f};
        __builtin_amdgcn_s_setprio(1);
        #pragma unroll
        for (int d = 0; d < 4; ++d) {
          short8 kf0 = *reinterpret_cast<const short8*>(
              &Ks[kbuf][l15][(((d << 2) + g) ^ l15) << 3]);
          short8 kf1 = *reinterpret_cast<const short8*>(
              &Ks[kbuf][16 + l15][(((d << 2) + g) ^ l15) << 3]);
          sc0 = __builtin_amdgcn_mfma_f32_16x16x32_bf16(kf0, qf[d], sc0, 0, 0, 0);
          sc1 = __builtin_amdgcn_mfma_f32_16x16x32_bf16(kf1, qf[d], sc1, 0, 0, 0);
        }
        sc0 = __builtin_amdgcn_mfma_f32_16x16x32_bf16(kr00, qf[4], sc0, 0, 0, 0);
        sc1 = __builtin_amdgcn_mfma_f32_16x16x32_bf16(kr10, qf[4], sc1, 0, 0, 0);
        sc0 = __builtin_amdgcn_mfma_f32_16x16x32_bf16(kr01, qf[5], sc0, 0, 0, 0);
        sc1 = __builtin_amdgcn_mfma_f32_16x16x32_bf16(kr11, qf[5], sc1, 0, 0, 0);
        __builtin_amdgcn_s_setprio(0);

        // scale + causal mask; lane holds q=srow, kv = kvb + {4g+r, 16+4g+r}
        float pp[8];
        float tmax = -1e30f;
        #pragma unroll
        for (int r = 0; r < 4; ++r) {
          int kv0i = kvb + (g << 2) + r;
          float s0 = sc0[r] * SCALE_F;
          if (kv0i > srow) s0 = -1e30f;
          float s1 = sc1[r] * SCALE_F;
          if (kv0i + 16 > srow) s1 = -1e30f;
          pp[r] = s0; pp[4 + r] = s1;
          tmax = fmaxf(tmax, fmaxf(s0, s1));
        }
        tmax = fmaxf(tmax, __shfl_xor(tmax, 16));
        tmax = fmaxf(tmax, __shfl_xor(tmax, 32));  // per-q max (q = l15), lane-local now

        // defer-max: only rescale when some q's max grew past THR=8
        float mm = mrun;
        bool rescale = !__all(tmax <= mrun + 8.f);
        float scold = 1.f;
        if (rescale) {
          mm = fmaxf(mrun, tmax);
          scold = __expf(mrun - mm);
          mrun = mm;
        }
        float ts = 0.f;
        #pragma unroll
        for (int i = 0; i < 8; ++i) { pp[i] = __expf(pp[i] - mm); ts += pp[i]; }
        ts += __shfl_xor(ts, 16);
        ts += __shfl_xor(ts, 32);
        lsum = lsum * scold + ts;

        // pack P to bf16x2; redistribute so lane holds P[q=l15][kv=8g+e]
        unsigned int w00 = (unsigned int)f2bf(pp[0]) | ((unsigned int)f2bf(pp[1]) << 16);
        unsigned int w01 = (unsigned int)f2bf(pp[2]) | ((unsigned int)f2bf(pp[3]) << 16);
        unsigned int w10 = (unsigned int)f2bf(pp[4]) | ((unsigned int)f2bf(pp[5]) << 16);
        unsigned int w11 = (unsigned int)f2bf(pp[6]) | ((unsigned int)f2bf(pp[7]) << 16);
        const int hsel = g >> 1;
        const int asel = (g << 1) & 3;
        const int src0 = (asel << 4) + l15, src1 = ((asel + 1) << 4) + l15;
        unsigned int s00 = (unsigned int)__shfl((int)w00, src0);
        unsigned int s01 = (unsigned int)__shfl((int)w01, src0);
        unsigned int s10 = (unsigned int)__shfl((int)w10, src0);
        unsigned int s11 = (unsigned int)__shfl((int)w11, src0);
        unsigned int t00 = (unsigned int)__shfl((int)w00, src1);
        unsigned int t01 = (unsigned int)__shfl((int)w01, src1);
        unsigned int t10 = (unsigned int)__shfl((int)w10, src1);
        unsigned int t11 = (unsigned int)__shfl((int)w11, src1);
        union { unsigned int u[4]; short8 v; } pa2;
        pa2.u[0] = hsel ? s10 : s00;
        pa2.u[1] = hsel ? s11 : s01;
        pa2.u[2] = hsel ? t10 : t00;
        pa2.u[3] = hsel ? t11 : t01;

        // O^T PV: acc[vg] = V^T-frag (A) x P^T-frag (B); rescale is lane-local
        __builtin_amdgcn_s_setprio(1);
        if (rescale) {
          #pragma unroll
          for (int vg = 0; vg < 8; ++vg) acc[vg] *= scold;
        }
        #pragma unroll
        for (int vg = 0; vg < 8; ++vg) {
          short8 vb = *reinterpret_cast<const short8*>(&Vt[kbuf][(vg << 4) + l15][g << 3]);
          acc[vg] = __builtin_amdgcn_mfma_f32_16x16x32_bf16(vb, pa2.v, acc[vg], 0, 0, 0);
        }
        __builtin_amdgcn_s_setprio(0);
      }

      // ---- write prefetched V tiles ----
      if (doA) {
        const unsigned short* pa = reinterpret_cast<const unsigned short*>(&vA);
        #pragma unroll
        for (int j = 0; j < 8; ++j) Vt[tA & 3][vcc + j][vkv] = pa[j];
      }
      if (doB) {
        const unsigned short* pb = reinterpret_cast<const unsigned short*>(&vB);
        #pragma unroll
        for (int j = 0; j < 8; ++j) Vt[tB & 3][vcc + j][vkv] = pb[j];
      }
      __syncthreads();
    }

    // ---- merge parity groups; acc = O^T[vcol=16vg+4g+r][q=l15], m/l lane-local ----
    if (e == 1) {
      #pragma unroll
      for (int vg = 0; vg < 8; ++vg)
        #pragma unroll
        for (int r = 0; r < 4; ++r)
          Msh[((s << 7) + (vg << 4) + (g << 2) + r) * 17 + l15] = acc[vg][r];
      if (g == 0) {
        Msh[4 * 128 * 17 + ((s << 4) + l15) * 2 + 0] = mrun;
        Msh[4 * 128 * 17 + ((s << 4) + l15) * 2 + 1] = lsum;
      }
    }
    __syncthreads();
    if (e == 0) {
      float m1 = Msh[4 * 128 * 17 + ((s << 4) + l15) * 2 + 0];
      float l1 = Msh[4 * 128 * 17 + ((s << 4) + l15) * 2 + 1];
      float mm = fmaxf(mrun, m1);
      float ea = __expf(mrun - mm), eb = __expf(m1 - mm);
      float linv = 1.f / (lsum * ea + l1 * eb);
      float alpha = ea * linv, beta = eb * linv;
      const size_t orow = (bsb + srow) * 2048 + h * 128;
      #pragma unroll
      for (int vg = 0; vg < 8; ++vg) {
        ushort4v o;
        #pragma unroll
        for (int r = 0; r < 4; ++r) {
          float v = acc[vg][r] * alpha +
                    Msh[((s << 7) + (vg << 4) + (g << 2) + r) * 17 + l15] * beta;
          o[r] = f2bf(v);
        }
        *reinterpret_cast<ushort4v*>(&attn_out[orow + (vg << 4) + (g << 2)]) = o;
      }
    }
  }
}

// ---------------- launch ----------------

extern "C" void kernel_launch(void* const* d_in, const int* in_sizes, int n_in,
                              void* d_out, int out_size, void* d_ws, size_t ws_size,
                              hipStream_t stream) {
  (void)in_sizes; (void)n_in; (void)out_size; (void)ws_size;
  const float* x = (const float*)d_in[0];
  const float* freq = (const float*)d_in[1];
  // d_in[2] = mask: always causal tril -> handled analytically
  const float* w_dq = (const float*)d_in[3];
  const float* b_dq = (const float*)d_in[4];
  const float* w_uq = (const float*)d_in[5];
  const float* b_uq = (const float*)d_in[6];
  const float* w_qr = (const float*)d_in[7];
  const float* b_qr = (const float*)d_in[8];
  const float* w_dkv = (const float*)d_in[9];
  const float* b_dkv = (const float*)d_in[10];
  const float* w_ukv = (const float*)d_in[11];
  const float* b_ukv = (const float*)d_in[12];
  const float* w_kr = (const float*)d_in[13];
  const float* b_kr = (const float*)d_in[14];
  const float* w_o = (const float*)d_in[15];
  const float* b_o = (const float*)d_in[16];

  char* ws = (char*)d_ws;
  size_t off = 0;
  auto alloc = [&](size_t bytes) {
    char* p = ws + off;
    off += (bytes + 255) & ~(size_t)255;
    return p;
  };
  unsigned short* x_bf   = (unsigned short*)alloc((size_t)4096 * 2048 * 2);
  unsigned short* wd_t   = (unsigned short*)alloc((size_t)1344 * 2048 * 2);  // dq|dkv|kr rows
  unsigned short* wqc_t  = (unsigned short*)alloc((size_t)3072 * 768 * 2);
  unsigned short* wukv_t = (unsigned short*)alloc((size_t)4096 * 512 * 2);
  unsigned short* wo_t   = (unsigned short*)alloc((size_t)2048 * 2048 * 2);
  float* tab             = (float*)alloc((size_t)2048 * 32 * 2 * 4);
  float* bcat            = (float*)alloc((size_t)3072 * 4);
  float* ball            = (float*)alloc((size_t)1344 * 4);
  unsigned short* c_all  = (unsigned short*)alloc((size_t)4096 * 1344 * 2);  // c_q|c_kv|kr_raw
  unsigned short* krro   = (unsigned short*)alloc((size_t)4096 * 64 * 2);
  unsigned short* q_raw  = (unsigned short*)alloc((size_t)4096 * 3072 * 2);
  unsigned short* kv_raw = (unsigned short*)alloc((size_t)4096 * 4096 * 2);
  unsigned short* attn   = (unsigned short*)alloc((size_t)4096 * 2048 * 2);

  hipMemcpyAsync(bcat, b_uq, 2048 * sizeof(float), hipMemcpyDeviceToDevice, stream);
  hipMemcpyAsync(bcat + 2048, b_qr, 1024 * sizeof(float), hipMemcpyDeviceToDevice, stream);
  hipMemcpyAsync(ball, b_dq, 768 * sizeof(float), hipMemcpyDeviceToDevice, stream);
  hipMemcpyAsync(ball + 768, b_dkv, 512 * sizeof(float), hipMemcpyDeviceToDevice, stream);
  hipMemcpyAsync(ball + 1280, b_kr, 64 * sizeof(float), hipMemcpyDeviceToDevice, stream);

  k_cast_bf16<<<dim3(8192), dim3(256), 0, stream>>>(x, x_bf, 4096 * 2048 / 4);
  k_rope_table<<<dim3(256), dim3(256), 0, stream>>>(freq, tab, 2048 * 32);

  // transposed bf16 weights; down-proj weights merged into wd_t rows [dq|dkv|kr]
  k_transpose_cast<<<dim3(768 / 64, 2048 / 64), dim3(256), 0, stream>>>(w_dq, wd_t, 2048, 768);
  k_transpose_cast<<<dim3(512 / 64, 2048 / 64), dim3(256), 0, stream>>>(
      w_dkv, wd_t + (size_t)768 * 2048, 2048, 512);
  k_transpose_cast<<<dim3(1, 2048 / 64), dim3(256), 0, stream>>>(
      w_kr, wd_t + (size_t)1280 * 2048, 2048, 64);
  k_transpose_cast<<<dim3(2048 / 64, 768 / 64), dim3(256), 0, stream>>>(w_uq, wqc_t, 768, 2048);
  k_transpose_cast<<<dim3(1024 / 64, 768 / 64), dim3(256), 0, stream>>>(
      w_qr, wqc_t + (size_t)2048 * 768, 768, 1024);
  k_transpose_cast<<<dim3(4096 / 64, 512 / 64), dim3(256), 0, stream>>>(w_ukv, wukv_t, 512, 4096);
  k_transpose_cast<<<dim3(2048 / 64, 2048 / 64), dim3(256), 0, stream>>>(w_o, wo_t, 2048, 2048);

  // single merged down-projection: x @ [w_dq|w_dkv|w_kr] -> c_all [4096][1344]
  k_gemm_bt<1><<<dim3(11, 32), dim3(256), 0, stream>>>(
      x_bf, wd_t, ball, c_all, 4096, 1344, 2048, 2048, 1344);
  k_rope_kr<<<dim3(512), dim3(256), 0, stream>>>(c_all + 1280, 1344, tab, krro, 4096 * 32);

  // up-projections
  k_gemm_bt<1><<<dim3(24, 32), dim3(256), 0, stream>>>(
      c_all, wqc_t, bcat, q_raw, 4096, 3072, 768, 1344, 3072);
  k_gemm_bt<1><<<dim3(32, 32), dim3(256), 0, stream>>>(
      c_all + 768, wukv_t, b_ukv, kv_raw, 4096, 4096, 512, 1344, 4096);

  // fused causal attention
  k_mla_attn<<<dim3(32, 16), dim3(512), 0, stream>>>(q_raw, kv_raw, krro, tab, attn);

  // output projection -> f32
  k_gemm_bt<0><<<dim3(16, 32), dim3(256), 0, stream>>>(
      attn, wo_t, b_o, (float*)d_out, 4096, 2048, 2048, 2048, 2048);
}

// Round 5
// 328.696 us; speedup vs baseline: 2.0372x; 1.2266x over previous
//
#include <hip/hip_runtime.h>
#include <cstdint>
#include <cstddef>

#define S_LEN 2048
#define SCALE_F 0.07216878364870323f  // 1/sqrt(192)

typedef __attribute__((ext_vector_type(8))) short short8;
typedef __attribute__((ext_vector_type(4))) float f32x4;
typedef __attribute__((ext_vector_type(16))) float f32x16;
typedef __attribute__((ext_vector_type(4))) unsigned short ushort4v;

__device__ __forceinline__ unsigned short f2bf(float f) {
  unsigned int u = __builtin_bit_cast(unsigned int, f);
  u += 0x7FFFu + ((u >> 16) & 1u);
  return (unsigned short)(u >> 16);
}
__device__ __forceinline__ float bf2f(unsigned short h) {
  unsigned int u = ((unsigned int)h) << 16;
  return __builtin_bit_cast(float, u);
}
__device__ __forceinline__ unsigned int cvt_pk_bf16(float lo, float hi) {
  unsigned int r;
  asm("v_cvt_pk_bf16_f32 %0, %1, %2" : "=v"(r) : "v"(lo), "v"(hi));
  return r;
}

typedef const __attribute__((address_space(1))) void* gas_ptr;
typedef __attribute__((address_space(3))) void* las_ptr;
__device__ __forceinline__ void gload16(const void* g, void* l) {
  __builtin_amdgcn_global_load_lds((gas_ptr)g, (las_ptr)l, 16, 0, 0);
}

// ---------------- elementwise kernels ----------------

__global__ void k_cast_bf16(const float* __restrict__ src, unsigned short* __restrict__ dst, int n4) {
  int i = blockIdx.x * 256 + threadIdx.x;
  if (i >= n4) return;
  const float4 v = reinterpret_cast<const float4*>(src)[i];
  ushort4v o = { f2bf(v.x), f2bf(v.y), f2bf(v.z), f2bf(v.w) };
  reinterpret_cast<ushort4v*>(dst)[i] = o;
}

__global__ void k_rope_table(const float* __restrict__ freq, float* __restrict__ tab, int n) {
  int i = blockIdx.x * 256 + threadIdx.x;
  if (i >= n) return;
  float f = freq[i];
  tab[2 * i] = cosf(f);
  tab[2 * i + 1] = sinf(f);
}

// src: K x N f32  ->  dst: N x K bf16   (K, N multiples of 64)
__global__ __launch_bounds__(256) void k_transpose_cast(
    const float* __restrict__ src, unsigned short* __restrict__ dst, int K, int N) {
  __shared__ __align__(16) unsigned short tile[64][72];
  const int tid = threadIdx.x;
  const int kb = blockIdx.y * 64, nb = blockIdx.x * 64;
  #pragma unroll
  for (int i = 0; i < 4; ++i) {
    int idx = i * 256 + tid;
    int row = idx >> 4, c4 = (idx & 15) << 2;
    const float4 v = *reinterpret_cast<const float4*>(&src[(size_t)(kb + row) * N + nb + c4]);
    tile[row][c4 + 0] = f2bf(v.x);
    tile[row][c4 + 1] = f2bf(v.y);
    tile[row][c4 + 2] = f2bf(v.z);
    tile[row][c4 + 3] = f2bf(v.w);
  }
  __syncthreads();
  #pragma unroll
  for (int i = 0; i < 4; ++i) {
    int idx = i * 256 + tid;
    int n = idx >> 4, kc = (idx & 15) << 2;
    ushort4v o = { tile[kc + 0][n], tile[kc + 1][n], tile[kc + 2][n], tile[kc + 3][n] };
    *reinterpret_cast<ushort4v*>(&dst[(size_t)(nb + n) * K + kb + kc]) = o;
  }
}

__global__ void k_rope_kr(const unsigned short* __restrict__ src, int src_stride,
                          const float* __restrict__ tab,
                          unsigned short* __restrict__ out, int npairs) {
  int idx = blockIdx.x * 256 + threadIdx.x;
  if (idx >= npairs) return;
  int bs = idx >> 5, p = idx & 31;
  int s = bs & (S_LEN - 1);
  float c = tab[(s * 32 + p) * 2], sn = tab[(s * 32 + p) * 2 + 1];
  float x1 = bf2f(src[(size_t)bs * src_stride + 2 * p]);
  float x2 = bf2f(src[(size_t)bs * src_stride + 2 * p + 1]);
  out[bs * 64 + 2 * p] = f2bf(x1 * c - x2 * sn);
  out[bs * 64 + 2 * p + 1] = f2bf(x1 * sn + x2 * c);
}

// ---------------- GEMM (m97 structure): C[M,N] = A[M,K] * Bt[N,K]^T + bias ----------------
template <int OUT_BF16>
__global__ __launch_bounds__(256) void k_gemm_bt(
    const unsigned short* __restrict__ A, const unsigned short* __restrict__ Bt,
    const float* __restrict__ bias, void* __restrict__ Cout, int M, int N, int K,
    int lda, int ldc) {
  __shared__ __align__(16) unsigned short As[128 * 32];
  __shared__ __align__(16) unsigned short Bs[128 * 32];
  const int tid = threadIdx.x;
  const int lane = tid & 63, wid = tid >> 6;
  const int wr = wid >> 1, wc = wid & 1;
  const int m0 = blockIdx.y << 7, n0 = blockIdx.x << 7;
  const int l15 = lane & 15, g = lane >> 4;

  const int srow = (wid << 5) + (lane >> 2);
  const int scol = (lane & 3) << 3;
  const unsigned short* aptr0 = &A[(size_t)(m0 + srow) * lda + scol];
  const unsigned short* aptr1 = &A[(size_t)(m0 + srow + 16) * lda + scol];
  int br0 = n0 + srow;      if (br0 >= N) br0 = N - 1;
  int br1 = n0 + srow + 16; if (br1 >= N) br1 = N - 1;
  const unsigned short* bptr0 = &Bt[(size_t)br0 * K + scol];
  const unsigned short* bptr1 = &Bt[(size_t)br1 * K + scol];
  unsigned short* lA0 = &As[((wid << 1) + 0) << 9];
  unsigned short* lA1 = &As[((wid << 1) + 1) << 9];
  unsigned short* lB0 = &Bs[((wid << 1) + 0) << 9];
  unsigned short* lB1 = &Bs[((wid << 1) + 1) << 9];

  f32x4 acc[4][4];
  #pragma unroll
  for (int m = 0; m < 4; ++m)
    #pragma unroll
    for (int n = 0; n < 4; ++n) acc[m][n] = f32x4{0.f, 0.f, 0.f, 0.f};

  for (int k0 = 0; k0 < K; k0 += 32) {
    gload16(aptr0 + k0, lA0);
    gload16(aptr1 + k0, lA1);
    gload16(bptr0 + k0, lB0);
    gload16(bptr1 + k0, lB1);
    __syncthreads();
    short8 af[4], bfr[4];
    #pragma unroll
    for (int m = 0; m < 4; ++m)
      af[m] = *reinterpret_cast<const short8*>(&As[(((wr << 6) + (m << 4) + l15) << 5) + (g << 3)]);
    #pragma unroll
    for (int n = 0; n < 4; ++n)
      bfr[n] = *reinterpret_cast<const short8*>(&Bs[(((wc << 6) + (n << 4) + l15) << 5) + (g << 3)]);
    __builtin_amdgcn_s_setprio(1);
    #pragma unroll
    for (int m = 0; m < 4; ++m)
      #pragma unroll
      for (int n = 0; n < 4; ++n)
        acc[m][n] = __builtin_amdgcn_mfma_f32_16x16x32_bf16(af[m], bfr[n], acc[m][n], 0, 0, 0);
    __builtin_amdgcn_s_setprio(0);
    __syncthreads();
  }
  #pragma unroll
  for (int n = 0; n < 4; ++n) {
    int col = n0 + (wc << 6) + (n << 4) + l15;
    if (col >= N) continue;
    float bv = bias[col];
    #pragma unroll
    for (int m = 0; m < 4; ++m) {
      int rowb = m0 + (wr << 6) + (m << 4) + (g << 2);
      #pragma unroll
      for (int r = 0; r < 4; ++r) {
        float v = acc[m][n][r] + bv;
        if (OUT_BF16)
          reinterpret_cast<unsigned short*>(Cout)[(size_t)(rowb + r) * ldc + col] = f2bf(v);
        else
          reinterpret_cast<float*>(Cout)[(size_t)(rowb + r) * ldc + col] = v;
      }
    }
  }
}

// ---------------- fused causal flash attention (32x32 MFMA, swapped QK, O^T) ----------------
// grid (B*NH, 8), block 512 = 8 waves: 4 q-strips (s, 32 q each) x 2 KV-parity groups (e).
// Block handles chunk pair {c, 15-c} sequentially (uniform work). KV tile = 32, 4-buf rotation.
// QK: mfma(A=K, B=Q) -> P^T in regs: lane holds 16 kv values for q=lane&31 (lane-local softmax).
// PV: mfma(A=V^T, B=P^T) -> acc = O^T[v][q]; rescale/normalize lane-local. Flash merge of parities.
__global__ __launch_bounds__(512, 2) void k_mla_attn(
    const unsigned short* __restrict__ q_raw, const unsigned short* __restrict__ kv_raw,
    const unsigned short* __restrict__ krro, const float* __restrict__ tab,
    unsigned short* __restrict__ attn_out) {
  __shared__ __align__(16) unsigned char smem[73728];
  unsigned short* KcB = reinterpret_cast<unsigned short*>(smem);            // [4][32][128] 32KB
  unsigned short* VtB = reinterpret_cast<unsigned short*>(smem + 32768);    // [4][128][40] 40KB
  float* Msh = reinterpret_cast<float*>(smem);  // merge: [4 strips][128 v][33] + ml @16896

  const int tid = threadIdx.x;
  const int lane = tid & 63, w = tid >> 6;
  const int s = w & 3, e = w >> 2;
  const int l31 = lane & 31, hi = lane >> 5;
  const int hi8 = hi << 3;
  const int bh = blockIdx.x, b = bh >> 4, h = bh & 15;
  const size_t bsb = (size_t)b * S_LEN;
  const int p = blockIdx.y;

  // V staging slot: 512 threads = 32 kv x 16 vg, one int4 (8 u16) each
  const int vkv = l31;
  const int vg = (w << 1) | hi;

  // Kc staging: group-of-4-waves stages one 32x128 tile; wave covers rows 8s..8s+7 (2 gload16)
  const int krow0 = (s << 3) + (lane >> 4);
  const int kunit = lane & 15;

  for (int half = 0; half < 2; ++half) {
    const int chunk = half ? (15 - p) : p;
    const int q0 = (chunk << 7) + (s << 5);
    const int srow = q0 + l31;
    const int ntb = (chunk << 2) + 4;
    const int U = ntb >> 1;
    const int nt_w = (q0 + 63) >> 5;

    __syncthreads();  // staging vs previous chunk's merge/epilogue

    // ---- Q fragments: lane holds Q[d = 16ks+8hi+e][q=l31]; rope on rotary frags ----
    short8 qf[12];
    {
      const size_t qrow = (bsb + q0 + l31) * 3072;
      #pragma unroll
      for (int ks = 0; ks < 8; ++ks)
        qf[ks] = *reinterpret_cast<const short8*>(&q_raw[qrow + h * 128 + ks * 16 + hi8]);
      #pragma unroll
      for (int f = 0; f < 4; ++f) {
        short8 rv = *reinterpret_cast<const short8*>(
            &q_raw[qrow + 2048 + h * 64 + f * 16 + hi8]);
        int pi0 = 8 * f + 4 * hi;
        union { unsigned short us[8]; short8 v; } uq;
        #pragma unroll
        for (int j = 0; j < 4; ++j) {
          float c = tab[(srow * 32 + pi0 + j) * 2];
          float sn = tab[(srow * 32 + pi0 + j) * 2 + 1];
          float x1 = bf2f((unsigned short)rv[2 * j]);
          float x2 = bf2f((unsigned short)rv[2 * j + 1]);
          uq.us[2 * j] = f2bf(x1 * c - x2 * sn);
          uq.us[2 * j + 1] = f2bf(x1 * sn + x2 * c);
        }
        qf[8 + f] = uq.v;
      }
    }

    f32x16 acc[4];
    #pragma unroll
    for (int a = 0; a < 4; ++a)
      #pragma unroll
      for (int r = 0; r < 16; ++r) acc[a][r] = 0.f;
    float mrun = -1e30f, lsum = 0.f;

    // ---- prologue: group e stages Kc tile e; all threads stage V tiles 0,1 ----
    {
      const int ts = e;
      gload16(&kv_raw[(bsb + (ts << 5) + krow0) * 4096 + h * 256 + (kunit ^ (krow0 & 15)) * 8],
              &KcB[(ts << 12) + ((s << 3) << 7)]);
      gload16(&kv_raw[(bsb + (ts << 5) + krow0 + 4) * 4096 + h * 256 + (kunit ^ ((krow0 + 4) & 15)) * 8],
              &KcB[(ts << 12) + (((s << 3) + 4) << 7)]);
      int4 v0 = *reinterpret_cast<const int4*>(&kv_raw[(bsb + vkv) * 4096 + h * 256 + 128 + vg * 8]);
      int4 v1 = *reinterpret_cast<const int4*>(&kv_raw[(bsb + 32 + vkv) * 4096 + h * 256 + 128 + vg * 8]);
      const unsigned short* p0 = reinterpret_cast<const unsigned short*>(&v0);
      const unsigned short* p1 = reinterpret_cast<const unsigned short*>(&v1);
      #pragma unroll
      for (int j = 0; j < 8; ++j) VtB[0 * 5120 + (vg * 8 + j) * 40 + vkv] = p0[j];
      #pragma unroll
      for (int j = 0; j < 8; ++j) VtB[1 * 5120 + (vg * 8 + j) * 40 + vkv] = p1[j];
    }
    __syncthreads();

    for (int u = 0; u < U; ++u) {
      // ---- issue Kc prefetch for tile 2u+2+e ----
      {
        int tsK = (u << 1) + 2 + e;
        if (tsK < ntb) {
          int buf = tsK & 3;
          gload16(&kv_raw[(bsb + (tsK << 5) + krow0) * 4096 + h * 256 + (kunit ^ (krow0 & 15)) * 8],
                  &KcB[(buf << 12) + ((s << 3) << 7)]);
          gload16(&kv_raw[(bsb + (tsK << 5) + krow0 + 4) * 4096 + h * 256 + (kunit ^ ((krow0 + 4) & 15)) * 8],
                  &KcB[(buf << 12) + (((s << 3) + 4) << 7)]);
        }
      }
      int4 vA, vB;
      const int tA = (u << 1) + 2, tB = (u << 1) + 3;
      const bool doA = tA < ntb, doB = tB < ntb;
      if (doA) vA = *reinterpret_cast<const int4*>(
          &kv_raw[(bsb + (tA << 5) + vkv) * 4096 + h * 256 + 128 + vg * 8]);
      if (doB) vB = *reinterpret_cast<const int4*>(
          &kv_raw[(bsb + (tB << 5) + vkv) * 4096 + h * 256 + 128 + vg * 8]);

      // ---- compute my tile t = 2u+e ----
      const int t = (u << 1) + e;
      if (t < nt_w) {
        const int kvb = t << 5;
        const int kbuf = t & 3;
        // rotary K fragments from global (L2-hot)
        short8 krf[4];
        #pragma unroll
        for (int f = 0; f < 4; ++f)
          krf[f] = *reinterpret_cast<const short8*>(
              &krro[(bsb + kvb + l31) * 64 + f * 16 + hi8]);

        // QK: two independent accumulation chains over d
        f32x16 sca, scb;
        #pragma unroll
        for (int r = 0; r < 16; ++r) { sca[r] = 0.f; scb[r] = 0.f; }
        __builtin_amdgcn_s_setprio(1);
        #pragma unroll
        for (int j = 0; j < 4; ++j) {
          short8 k0 = *reinterpret_cast<const short8*>(
              &KcB[(kbuf << 12) + (l31 << 7) + ((((2 * (2 * j)) | hi) ^ (l31 & 15)) << 3)]);
          sca = __builtin_amdgcn_mfma_f32_32x32x16_bf16(k0, qf[2 * j], sca, 0, 0, 0);
          short8 k1 = *reinterpret_cast<const short8*>(
              &KcB[(kbuf << 12) + (l31 << 7) + ((((2 * (2 * j + 1)) | hi) ^ (l31 & 15)) << 3)]);
          scb = __builtin_amdgcn_mfma_f32_32x32x16_bf16(k1, qf[2 * j + 1], scb, 0, 0, 0);
        }
        sca = __builtin_amdgcn_mfma_f32_32x32x16_bf16(krf[0], qf[8], sca, 0, 0, 0);
        scb = __builtin_amdgcn_mfma_f32_32x32x16_bf16(krf[1], qf[9], scb, 0, 0, 0);
        sca = __builtin_amdgcn_mfma_f32_32x32x16_bf16(krf[2], qf[10], sca, 0, 0, 0);
        scb = __builtin_amdgcn_mfma_f32_32x32x16_bf16(krf[3], qf[11], scb, 0, 0, 0);
        __builtin_amdgcn_s_setprio(0);
        f32x16 sc = sca + scb;

        // scale + causal mask (diagonal tiles only); lane q=srow, reg r -> kv
        #pragma unroll
        for (int r = 0; r < 16; ++r) sc[r] *= SCALE_F;
        if (kvb + 31 > q0) {
          #pragma unroll
          for (int r = 0; r < 16; ++r) {
            int kv = kvb + (r & 3) + ((r >> 2) << 3) + (hi << 2);
            if (kv > srow) sc[r] = -1e30f;
          }
        }
        // lane-local row max (other 16 kv live in partner lane, same q)
        float m0 = fmaxf(fmaxf(sc[0], sc[1]), fmaxf(sc[2], sc[3]));
        float m1 = fmaxf(fmaxf(sc[4], sc[5]), fmaxf(sc[6], sc[7]));
        float m2 = fmaxf(fmaxf(sc[8], sc[9]), fmaxf(sc[10], sc[11]));
        float m3 = fmaxf(fmaxf(sc[12], sc[13]), fmaxf(sc[14], sc[15]));
        float tmax = fmaxf(fmaxf(m0, m1), fmaxf(m2, m3));
        tmax = fmaxf(tmax, __shfl_xor(tmax, 32));

        bool rescale = !__all(tmax <= mrun + 8.f);
        float scold = 1.f;
        if (rescale) {
          float mm = fmaxf(mrun, tmax);
          scold = __expf(mrun - mm);
          mrun = mm;
        }
        float pe[16];
        float ts = 0.f;
        #pragma unroll
        for (int r = 0; r < 16; ++r) { pe[r] = __expf(sc[r] - mrun); ts += pe[r]; }
        ts += __shfl_xor(ts, 32);
        lsum = lsum * scold + ts;

        // P -> bf16 B-fragments: per k-slot exchange across lane^32
        if (rescale) {
          #pragma unroll
          for (int a = 0; a < 4; ++a)
            #pragma unroll
            for (int r = 0; r < 16; ++r) acc[a][r] *= scold;
        }
        #pragma unroll
        for (int ks = 0; ks < 2; ++ks) {
          unsigned int X0 = cvt_pk_bf16(pe[8 * ks + 0], pe[8 * ks + 1]);
          unsigned int X1 = cvt_pk_bf16(pe[8 * ks + 2], pe[8 * ks + 3]);
          unsigned int Y0 = cvt_pk_bf16(pe[8 * ks + 4], pe[8 * ks + 5]);
          unsigned int Y1 = cvt_pk_bf16(pe[8 * ks + 6], pe[8 * ks + 7]);
          unsigned int send0 = hi ? X0 : Y0;
          unsigned int send1 = hi ? X1 : Y1;
          unsigned int recv0 = (unsigned int)__shfl_xor((int)send0, 32);
          unsigned int recv1 = (unsigned int)__shfl_xor((int)send1, 32);
          union { unsigned int u[4]; short8 v; } pa;
          pa.u[0] = hi ? recv0 : X0;
          pa.u[1] = hi ? recv1 : X1;
          pa.u[2] = hi ? Y0 : recv0;
          pa.u[3] = hi ? Y1 : recv1;
          __builtin_amdgcn_s_setprio(1);
          #pragma unroll
          for (int a = 0; a < 4; ++a) {
            short8 va = *reinterpret_cast<const short8*>(
                &VtB[kbuf * 5120 + (32 * a + l31) * 40 + ks * 16 + hi8]);
            acc[a] = __builtin_amdgcn_mfma_f32_32x32x16_bf16(va, pa.v, acc[a], 0, 0, 0);
          }
          __builtin_amdgcn_s_setprio(0);
        }
      }

      // ---- write prefetched V tiles (issue-early / write-late) ----
      if (doA) {
        const unsigned short* pv = reinterpret_cast<const unsigned short*>(&vA);
        #pragma unroll
        for (int j = 0; j < 8; ++j) VtB[(tA & 3) * 5120 + (vg * 8 + j) * 40 + vkv] = pv[j];
      }
      if (doB) {
        const unsigned short* pv = reinterpret_cast<const unsigned short*>(&vB);
        #pragma unroll
        for (int j = 0; j < 8; ++j) VtB[(tB & 3) * 5120 + (vg * 8 + j) * 40 + vkv] = pv[j];
      }
      __syncthreads();
    }

    // ---- flash merge of parity groups; acc = O^T[v][q=l31], m/l lane-local ----
    if (e == 1) {
      #pragma unroll
      for (int a = 0; a < 4; ++a)
        #pragma unroll
        for (int r = 0; r < 16; ++r) {
          int v = 32 * a + (r & 3) + ((r >> 2) << 3) + (hi << 2);
          Msh[((s << 7) + v) * 33 + l31] = acc[a][r];
        }
      if (hi == 0) {
        Msh[16896 + ((s << 5) + l31) * 2 + 0] = mrun;
        Msh[16896 + ((s << 5) + l31) * 2 + 1] = lsum;
      }
    }
    __syncthreads();
    if (e == 0) {
      float m1 = Msh[16896 + ((s << 5) + l31) * 2 + 0];
      float l1 = Msh[16896 + ((s << 5) + l31) * 2 + 1];
      float mm = fmaxf(mrun, m1);
      float ea = __expf(mrun - mm), eb = __expf(m1 - mm);
      float linv = 1.f / (lsum * ea + l1 * eb);
      float al = ea * linv, be = eb * linv;
      // merge partner partials into acc (read all before transpose-buffer writes)
      #pragma unroll
      for (int a = 0; a < 4; ++a)
        #pragma unroll
        for (int r = 0; r < 16; ++r) {
          int v = 32 * a + (r & 3) + ((r >> 2) << 3) + (hi << 2);
          float part = Msh[((s << 7) + v) * 33 + l31];
          acc[a][r] = acc[a][r] * al + part * be;
        }
      // transpose O^T -> O via per-strip LDS region, then coalesced stores
      unsigned int* Tb = reinterpret_cast<unsigned int*>(smem) + s * 4224;
      #pragma unroll
      for (int a = 0; a < 4; ++a)
        #pragma unroll
        for (int j = 0; j < 8; ++j) {
          unsigned int word = cvt_pk_bf16(acc[a][2 * j], acc[a][2 * j + 1]);
          int wc = 16 * a + 2 * hi + (j & 1) + 4 * (j >> 1);
          Tb[l31 * 68 + wc] = word;
        }
      const unsigned char* Tbb = reinterpret_cast<const unsigned char*>(Tb);
      #pragma unroll
      for (int u2 = 0; u2 < 8; ++u2) {
        int qr = (u2 << 2) + (lane >> 4);
        int4 rd = *reinterpret_cast<const int4*>(&Tbb[qr * 272 + (lane & 15) * 16]);
        *reinterpret_cast<int4*>(
            &attn_out[(bsb + q0 + qr) * 2048 + h * 128 + (lane & 15) * 8]) = rd;
      }
    }
  }
}

// ---------------- launch ----------------

extern "C" void kernel_launch(void* const* d_in, const int* in_sizes, int n_in,
                              void* d_out, int out_size, void* d_ws, size_t ws_size,
                              hipStream_t stream) {
  (void)in_sizes; (void)n_in; (void)out_size; (void)ws_size;
  const float* x = (const float*)d_in[0];
  const float* freq = (const float*)d_in[1];
  // d_in[2] = mask: always causal tril -> handled analytically
  const float* w_dq = (const float*)d_in[3];
  const float* b_dq = (const float*)d_in[4];
  const float* w_uq = (const float*)d_in[5];
  const float* b_uq = (const float*)d_in[6];
  const float* w_qr = (const float*)d_in[7];
  const float* b_qr = (const float*)d_in[8];
  const float* w_dkv = (const float*)d_in[9];
  const float* b_dkv = (const float*)d_in[10];
  const float* w_ukv = (const float*)d_in[11];
  const float* b_ukv = (const float*)d_in[12];
  const float* w_kr = (const float*)d_in[13];
  const float* b_kr = (const float*)d_in[14];
  const float* w_o = (const float*)d_in[15];
  const float* b_o = (const float*)d_in[16];

  char* ws = (char*)d_ws;
  size_t off = 0;
  auto alloc = [&](size_t bytes) {
    char* p = ws + off;
    off += (bytes + 255) & ~(size_t)255;
    return p;
  };
  unsigned short* x_bf   = (unsigned short*)alloc((size_t)4096 * 2048 * 2);
  unsigned short* wd_t   = (unsigned short*)alloc((size_t)1344 * 2048 * 2);  // dq|dkv|kr rows
  unsigned short* wqc_t  = (unsigned short*)alloc((size_t)3072 * 768 * 2);
  unsigned short* wukv_t = (unsigned short*)alloc((size_t)4096 * 512 * 2);
  unsigned short* wo_t   = (unsigned short*)alloc((size_t)2048 * 2048 * 2);
  float* tab             = (float*)alloc((size_t)2048 * 32 * 2 * 4);
  float* bcat            = (float*)alloc((size_t)3072 * 4);
  float* ball            = (float*)alloc((size_t)1344 * 4);
  unsigned short* c_all  = (unsigned short*)alloc((size_t)4096 * 1344 * 2);  // c_q|c_kv|kr_raw
  unsigned short* krro   = (unsigned short*)alloc((size_t)4096 * 64 * 2);
  unsigned short* q_raw  = (unsigned short*)alloc((size_t)4096 * 3072 * 2);
  unsigned short* kv_raw = (unsigned short*)alloc((size_t)4096 * 4096 * 2);
  unsigned short* attn   = (unsigned short*)alloc((size_t)4096 * 2048 * 2);

  hipMemcpyAsync(bcat, b_uq, 2048 * sizeof(float), hipMemcpyDeviceToDevice, stream);
  hipMemcpyAsync(bcat + 2048, b_qr, 1024 * sizeof(float), hipMemcpyDeviceToDevice, stream);
  hipMemcpyAsync(ball, b_dq, 768 * sizeof(float), hipMemcpyDeviceToDevice, stream);
  hipMemcpyAsync(ball + 768, b_dkv, 512 * sizeof(float), hipMemcpyDeviceToDevice, stream);
  hipMemcpyAsync(ball + 1280, b_kr, 64 * sizeof(float), hipMemcpyDeviceToDevice, stream);

  k_cast_bf16<<<dim3(8192), dim3(256), 0, stream>>>(x, x_bf, 4096 * 2048 / 4);
  k_rope_table<<<dim3(256), dim3(256), 0, stream>>>(freq, tab, 2048 * 32);

  k_transpose_cast<<<dim3(768 / 64, 2048 / 64), dim3(256), 0, stream>>>(w_dq, wd_t, 2048, 768);
  k_transpose_cast<<<dim3(512 / 64, 2048 / 64), dim3(256), 0, stream>>>(
      w_dkv, wd_t + (size_t)768 * 2048, 2048, 512);
  k_transpose_cast<<<dim3(1, 2048 / 64), dim3(256), 0, stream>>>(
      w_kr, wd_t + (size_t)1280 * 2048, 2048, 64);
  k_transpose_cast<<<dim3(2048 / 64, 768 / 64), dim3(256), 0, stream>>>(w_uq, wqc_t, 768, 2048);
  k_transpose_cast<<<dim3(1024 / 64, 768 / 64), dim3(256), 0, stream>>>(
      w_qr, wqc_t + (size_t)2048 * 768, 768, 1024);
  k_transpose_cast<<<dim3(4096 / 64, 512 / 64), dim3(256), 0, stream>>>(w_ukv, wukv_t, 512, 4096);
  k_transpose_cast<<<dim3(2048 / 64, 2048 / 64), dim3(256), 0, stream>>>(w_o, wo_t, 2048, 2048);

  // single merged down-projection: x @ [w_dq|w_dkv|w_kr] -> c_all [4096][1344]
  k_gemm_bt<1><<<dim3(11, 32), dim3(256), 0, stream>>>(
      x_bf, wd_t, ball, c_all, 4096, 1344, 2048, 2048, 1344);
  k_rope_kr<<<dim3(512), dim3(256), 0, stream>>>(c_all + 1280, 1344, tab, krro, 4096 * 32);

  // up-projections
  k_gemm_bt<1><<<dim3(24, 32), dim3(256), 0, stream>>>(
      c_all, wqc_t, bcat, q_raw, 4096, 3072, 768, 1344, 3072);
  k_gemm_bt<1><<<dim3(32, 32), dim3(256), 0, stream>>>(
      c_all + 768, wukv_t, b_ukv, kv_raw, 4096, 4096, 512, 1344, 4096);

  // fused causal attention: 32x32 MFMA structure, uniform chunk-pair blocks
  k_mla_attn<<<dim3(32, 8), dim3(512), 0, stream>>>(q_raw, kv_raw, krro, tab, attn);

  // output projection -> f32
  k_gemm_bt<0><<<dim3(16, 32), dim3(256), 0, stream>>>(
      attn, wo_t, b_o, (float*)d_out, 4096, 2048, 2048, 2048, 2048);
}